// Round 2
// 1202.902 us; speedup vs baseline: 1.5757x; 1.5757x over previous
//
#include <hip/hip_runtime.h>
#include <hip/hip_bf16.h>

typedef __hip_bfloat16 bf16;
typedef __attribute__((ext_vector_type(8))) short frag_ab;   // 8 bf16
typedef __attribute__((ext_vector_type(4))) float frag_cd;   // 4 fp32

__device__ __forceinline__ short f2bs(float f){
    bf16 h = __float2bfloat16(f); short s; __builtin_memcpy(&s, &h, 2); return s;
}
__device__ __forceinline__ unsigned pack2(float a, float b){
    return (unsigned)(unsigned short)f2bs(a) | (((unsigned)(unsigned short)f2bs(b)) << 16);
}
static inline int imin(int a, int b){ return a < b ? a : b; }

// ---------------------------------------------------------------------------
// Fold attention vectors into projection weights:
// Wf[k,g] = sum_d Wa[k,(g&7)*16+d] * att_g[(g&7)*16+d],  att_g = atd_pa (g<8) / atd_da
// bdot[g] = sum_d ba[(g&7)*16+d] * att_g[(g&7)*16+d]
__global__ void prep_fold(const float* __restrict__ Wa, const float* __restrict__ ba,
                          const float* __restrict__ atd_pa, const float* __restrict__ atd_da,
                          float* __restrict__ Wf, float* __restrict__ bdot)
{
    const int k = threadIdx.x;  // 0..127
    for (int g = 0; g < 16; g++){
        const float* att = (g < 8) ? atd_pa : atd_da;
        const int h = g & 7;
        float ssum = 0.f;
        for (int d = 0; d < 16; d++)
            ssum += Wa[k*128 + h*16 + d] * att[h*16 + d];
        Wf[k*16 + g] = ssum;
    }
    if (k < 16){
        const float* att = (k < 8) ? atd_pa : atd_da;
        const int h = k & 7;
        float sb = 0.f;
        for (int d = 0; d < 16; d++) sb += ba[h*16 + d] * att[h*16 + d];
        bdot[k] = sb;
    }
}

// ---------------------------------------------------------------------------
// Thin GEMM: a_d[n,g] = x[n,:] @ Wf[:,g] + bdot[g]   (g<8 -> a_pa, else a_da)
__global__ __launch_bounds__(256) void afold_kernel(
    const float* __restrict__ x,     // [Na,128]
    const float* __restrict__ Wf,    // [128,16]
    const float* __restrict__ bdot,  // [16]
    float* __restrict__ a_pa,        // [Na,8]
    float* __restrict__ a_da,        // [Na,8]
    int Na, int ntiles)
{
    __shared__ float WfT[16*132];
    __shared__ float xsr[16*132];
    __shared__ float bs[16];
    const int tid = threadIdx.x;
    for (int i = tid; i < 2048; i += 256){
        const int k = i >> 4, g = i & 15;
        WfT[g*132 + k] = Wf[k*16 + g];
    }
    if (tid < 16) bs[tid] = bdot[tid];
    const int r = tid >> 4, g = tid & 15;

    for (int tile = blockIdx.x; tile < ntiles; tile += gridDim.x){
        const int row0 = tile*16;
        __syncthreads();
        for (int i = tid; i < 512; i += 256){
            const int rr = i >> 5, c4 = (i & 31)*4;
            const int row = row0 + rr;
            float4 v = make_float4(0.f,0.f,0.f,0.f);
            if (row < Na) v = *(const float4*)&x[(size_t)row*128 + c4];
            *(float4*)&xsr[rr*132 + c4] = v;
        }
        __syncthreads();
        float acc = bs[g];
        #pragma unroll 4
        for (int k0 = 0; k0 < 128; k0 += 4){
            const float4 xv = *(const float4*)&xsr[r*132 + k0];
            const float4 wv = *(const float4*)&WfT[g*132 + k0];
            acc += xv.x*wv.x + xv.y*wv.y + xv.z*wv.z + xv.w*wv.w;
        }
        const int row = row0 + r;
        if (row < Na){
            if (g < 8) a_pa[(size_t)row*8 + g]     = acc;
            else       a_da[(size_t)row*8 + (g-8)] = acc;
        }
    }
}

// ---------------------------------------------------------------------------
// Projection for pat/diag (K=64): h = x@W+b (stored bf16), a_s dots.
__global__ __launch_bounds__(256) void proj64(
    const float* __restrict__ x,      // [N,64]
    const float* __restrict__ W,      // [64,128]
    const float* __restrict__ b,      // [128]
    const float* __restrict__ att0,   // [128]
    bf16*  __restrict__ h_out,        // [N,128]
    float* __restrict__ a0_out,       // [N,8]
    int N, int ntiles)
{
    constexpr int K = 64;
    __shared__ float Wsf[K*128];
    __shared__ float xs[32*K];
    const int tid = threadIdx.x;
    const int cg = tid & 31;
    const int rg = tid >> 5;

    for (int i = tid; i < K*32; i += 256)
        *(float4*)&Wsf[i*4] = *(const float4*)&W[i*4];

    float bc[4], at0v[4];
    #pragma unroll
    for (int u = 0; u < 4; u++){ bc[u] = b[cg*4+u]; at0v[u] = att0[cg*4+u]; }
    const int head = cg >> 2;

    for (int tile = blockIdx.x; tile < ntiles; tile += gridDim.x){
        const int row0 = tile*32;
        __syncthreads();
        for (int i = tid; i < 32*(K/4); i += 256){
            const int r  = i / (K/4);
            const int c4 = (i % (K/4))*4;
            const int row = row0 + r;
            float4 v = make_float4(0.f,0.f,0.f,0.f);
            if (row < N) v = *(const float4*)&x[(size_t)row*K + c4];
            *(float4*)&xs[r*K + c4] = v;
        }
        __syncthreads();

        float acc[4][4];
        #pragma unroll
        for (int j = 0; j < 4; j++){ acc[j][0]=acc[j][1]=acc[j][2]=acc[j][3]=0.f; }

        #pragma unroll 2
        for (int k0 = 0; k0 < K; k0 += 4){
            float xr[4][4];
            #pragma unroll
            for (int j = 0; j < 4; j++){
                const float4 v = *(const float4*)&xs[(rg*4+j)*K + k0];
                xr[j][0]=v.x; xr[j][1]=v.y; xr[j][2]=v.z; xr[j][3]=v.w;
            }
            #pragma unroll
            for (int kk = 0; kk < 4; kk++){
                const float4 wv = *(const float4*)&Wsf[(k0+kk)*128 + cg*4];
                #pragma unroll
                for (int j = 0; j < 4; j++){
                    acc[j][0] = fmaf(xr[j][kk], wv.x, acc[j][0]);
                    acc[j][1] = fmaf(xr[j][kk], wv.y, acc[j][1]);
                    acc[j][2] = fmaf(xr[j][kk], wv.z, acc[j][2]);
                    acc[j][3] = fmaf(xr[j][kk], wv.w, acc[j][3]);
                }
            }
        }

        #pragma unroll
        for (int j = 0; j < 4; j++){
            const int row = row0 + rg*4 + j;
            const bool valid = row < N;
            const float h0 = acc[j][0]+bc[0], h1 = acc[j][1]+bc[1];
            const float h2 = acc[j][2]+bc[2], h3 = acc[j][3]+bc[3];
            if (valid){
                h_out[(size_t)row*128 + cg*4+0] = __float2bfloat16(h0);
                h_out[(size_t)row*128 + cg*4+1] = __float2bfloat16(h1);
                h_out[(size_t)row*128 + cg*4+2] = __float2bfloat16(h2);
                h_out[(size_t)row*128 + cg*4+3] = __float2bfloat16(h3);
            }
            float p0 = h0*at0v[0] + h1*at0v[1] + h2*at0v[2] + h3*at0v[3];
            p0 += __shfl_down(p0, 2, 4);
            p0 += __shfl_down(p0, 1, 4);
            if (valid && (cg & 3) == 0) a0_out[(size_t)row*8 + head] = p0;
        }
    }
}

// ---------------------------------------------------------------------------
// Counting sort of edges by destination -> CSR, then gather-aggregate.
// Step 1: histogram counts per dst.
__global__ __launch_bounds__(256) void hist_kernel(
    const int* __restrict__ dst, int* __restrict__ cnt, int E)
{
    const int e = blockIdx.x*256 + threadIdx.x;
    if (e < E) atomicAdd(&cnt[dst[e]], 1);
}

// Step 2a: per-chunk (4096) block sums.
__global__ __launch_bounds__(256) void scan_bsum(
    const int* __restrict__ cnt, int* __restrict__ bsum, int n)
{
    __shared__ int red[256];
    const int base = blockIdx.x*4096;
    int s = 0;
    for (int i = threadIdx.x; i < 4096; i += 256){
        const int idx = base + i;
        s += (idx < n) ? cnt[idx] : 0;
    }
    red[threadIdx.x] = s; __syncthreads();
    for (int st = 128; st > 0; st >>= 1){
        if (threadIdx.x < st) red[threadIdx.x] += red[threadIdx.x + st];
        __syncthreads();
    }
    if (threadIdx.x == 0) bsum[blockIdx.x] = red[0];
}

// Step 2b: exclusive scan of block sums (nb <= 256), single block.
__global__ __launch_bounds__(256) void scan_excl(int* __restrict__ bsum, int nb)
{
    __shared__ int sh[256];
    const int t = threadIdx.x;
    sh[t] = (t < nb) ? bsum[t] : 0;
    __syncthreads();
    #pragma unroll
    for (int st = 1; st < 256; st <<= 1){
        const int u = (t >= st) ? sh[t - st] : 0;
        __syncthreads();
        sh[t] += u;
        __syncthreads();
    }
    if (t < nb) bsum[t] = t ? sh[t-1] : 0;
}

// Step 2c: per-chunk exclusive scan; writes rowptr and re-inits cnt as cursor.
__global__ __launch_bounds__(256) void scan_write(
    int* __restrict__ cnt,            // in: counts; out: cursor (= rowptr copy)
    const int* __restrict__ bsum,
    int* __restrict__ rowptr, int n)
{
    __shared__ int sh[256];
    const int t = threadIdx.x;
    const int base = blockIdx.x*4096 + t*16;
    int loc[16]; int s = 0;
    #pragma unroll
    for (int i = 0; i < 16; i += 4){
        int4 v = make_int4(0,0,0,0);
        if (base + i + 3 < n) v = *(const int4*)&cnt[base + i];
        else {
            if (base+i   < n) v.x = cnt[base+i];
            if (base+i+1 < n) v.y = cnt[base+i+1];
            if (base+i+2 < n) v.z = cnt[base+i+2];
            if (base+i+3 < n) v.w = cnt[base+i+3];
        }
        loc[i]   = s; s += v.x;
        loc[i+1] = s; s += v.y;
        loc[i+2] = s; s += v.z;
        loc[i+3] = s; s += v.w;
    }
    sh[t] = s; __syncthreads();
    #pragma unroll
    for (int st = 1; st < 256; st <<= 1){
        const int u = (t >= st) ? sh[t - st] : 0;
        __syncthreads();
        sh[t] += u;
        __syncthreads();
    }
    const int off = bsum[blockIdx.x] + (t ? sh[t-1] : 0);
    #pragma unroll
    for (int i = 0; i < 16; i++){
        const int idx = base + i;
        if (idx < n){
            const int v = off + loc[i];
            rowptr[idx] = v;
            cnt[idx]    = v;   // cursor for scatter
        }
    }
    if (blockIdx.x == gridDim.x-1 && t == 255) rowptr[n] = off + s;
}

// Step 3: scatter src ids into dst-sorted order.
__global__ __launch_bounds__(256) void scatter_kernel(
    const int* __restrict__ src, const int* __restrict__ dst,
    int* __restrict__ cursor, int* __restrict__ sorted_src, int E)
{
    const int e = blockIdx.x*256 + threadIdx.x;
    if (e < E){
        const int pos = atomicAdd(&cursor[dst[e]], 1);
        sorted_src[pos] = src[e];
    }
}

// Step 4: gather-aggregate. One wave per dst node; lane l owns dims 2l,2l+1.
// No atomics: o_out/s_out written exactly once, coalesced.
__global__ __launch_bounds__(256) void gather_kernel(
    const int* __restrict__ rowptr, const int* __restrict__ sorted_src,
    const float* __restrict__ a_s,    // [Ns,8]
    const float* __restrict__ a_d,    // [Na,8]
    const bf16*  __restrict__ h_src,  // [Ns,128]
    float* __restrict__ s_out,        // [Na,8]
    float* __restrict__ o_out,        // [Na,128]
    int Na)
{
    const int n = blockIdx.x*4 + (threadIdx.x >> 6);
    if (n >= Na) return;
    const int l = threadIdx.x & 63;
    const int h = l >> 3;                       // head of dims 2l,2l+1
    const int beg = rowptr[n], end = rowptr[n+1];
    const float ad = a_d[(size_t)n*8 + h];
    float acc0 = 0.f, acc1 = 0.f, ssum = 0.f;

    for (int base = beg; base < end; base += 64){
        const int nb = min(64, end - base);
        int sv = 0;
        if (base + l < end) sv = sorted_src[base + l];
        // software-pipelined: loads for edge k+1 issued before consuming edge k
        int sN = __shfl(sv, 0);
        float    as = a_s[(size_t)sN*8 + h];
        unsigned hv = *(const unsigned*)((const char*)h_src + (size_t)sN*256 + l*4);
        for (int k = 0; k < nb; k++){
            const float    as_c = as;
            const unsigned hv_c = hv;
            if (k + 1 < nb){
                const int sN2 = __shfl(sv, k + 1);
                as = a_s[(size_t)sN2*8 + h];
                hv = *(const unsigned*)((const char*)h_src + (size_t)sN2*256 + l*4);
            }
            float logit = as_c + ad;
            logit = logit >= 0.f ? logit : 0.2f*logit;    // leaky_relu(0.2)
            logit = fminf(fmaxf(logit, -30.f), 30.f);
            const float ee = __expf(logit);
            acc0 = fmaf(ee, __uint_as_float(hv_c << 16),         acc0);
            acc1 = fmaf(ee, __uint_as_float(hv_c & 0xffff0000u), acc1);
            ssum += ee;
        }
    }
    float2 st; st.x = acc0; st.y = acc1;
    *(float2*)&o_out[(size_t)n*128 + 2*l] = st;
    if ((l & 7) == 0) s_out[(size_t)n*8 + h] = ssum;
}

// ---------------------------------------------------------------------------
// Semantic attention GEMM via bf16 MFMA 16x16x32.
__global__ __launch_bounds__(256) void semw_mfma(
    const float* __restrict__ o0, const float* __restrict__ o1,
    const float* __restrict__ s0, const float* __restrict__ s1,
    const float* __restrict__ Wk, const float* __restrict__ bk,
    float* __restrict__ wsum, int Na, int ntiles)
{
    __shared__ short Bs[4*8*64*8];     // [k0i][n0i][lane][j] bf16, 32KB
    __shared__ short As[64*136];       // 64 rows x K=128 (stride 136), 17KB
    const int tid  = threadIdx.x;
    const int lane = tid & 63;
    const int w    = tid >> 6;
    const int quad = lane >> 4;
    const int m16  = lane & 15;
    const float* __restrict__ o = blockIdx.y ? o1 : o0;
    const float* __restrict__ s = blockIdx.y ? s1 : s0;

    for (int idx = tid; idx < 16384; idx += 256){
        const int j   = idx & 7;
        const int ln  = (idx >> 3) & 63;
        const int n0i = (idx >> 9) & 7;
        const int k0i = idx >> 12;
        const int k = k0i*32 + (ln >> 4)*8 + j;
        const int n = n0i*16 + (ln & 15);
        Bs[idx] = f2bs(Wk[k*128 + n]);
    }

    float bkc[8];
    #pragma unroll
    for (int n0i = 0; n0i < 8; n0i++) bkc[n0i] = bk[n0i*16 + m16];

    float colsum[8] = {0.f,0.f,0.f,0.f,0.f,0.f,0.f,0.f};

    for (int tile = blockIdx.x; tile < ntiles; tile += gridDim.x){
        const int row0 = tile*64;
        __syncthreads();
        for (int i = tid; i < 64*32; i += 256){
            const int r  = i >> 5;
            const int c4 = (i & 31)*4;
            const int row = row0 + r;
            float4 v = make_float4(0.f,0.f,0.f,0.f);
            if (row < Na){
                v = *(const float4*)&o[(size_t)row*128 + c4];
                const float inv = 1.f/(s[(size_t)row*8 + (c4>>4)] + 1e-16f);
                v.x = fmaxf(v.x*inv,0.f); v.y = fmaxf(v.y*inv,0.f);
                v.z = fmaxf(v.z*inv,0.f); v.w = fmaxf(v.w*inv,0.f);
            }
            const unsigned u0 = pack2(v.x, v.y);
            const unsigned u1 = pack2(v.z, v.w);
            uint2 uu = make_uint2(u0, u1);
            __builtin_memcpy(&As[r*136 + c4], &uu, 8);
        }
        __syncthreads();

        frag_cd acc[8];
        #pragma unroll
        for (int n0i = 0; n0i < 8; n0i++) acc[n0i] = (frag_cd){0.f,0.f,0.f,0.f};

        #pragma unroll
        for (int k0i = 0; k0i < 4; k0i++){
            frag_ab av = *(const frag_ab*)&As[(w*16 + m16)*136 + k0i*32 + quad*8];
            #pragma unroll
            for (int n0i = 0; n0i < 8; n0i++){
                frag_ab bv = *(const frag_ab*)&Bs[((k0i*8 + n0i)*64 + lane)*8];
                acc[n0i] = __builtin_amdgcn_mfma_f32_16x16x32_bf16(av, bv, acc[n0i], 0, 0, 0);
            }
        }

        #pragma unroll
        for (int n0i = 0; n0i < 8; n0i++){
            float part = 0.f;
            #pragma unroll
            for (int r = 0; r < 4; r++){
                const int row = row0 + w*16 + quad*4 + r;
                if (row < Na) part += tanhf(acc[n0i][r] + bkc[n0i]);
            }
            part += __shfl_down(part, 32);
            part += __shfl_down(part, 16);
            if (lane < 16) colsum[n0i] += part;
        }
    }
    if (lane < 16){
        float* wdst = wsum + blockIdx.y*128;
        #pragma unroll
        for (int n0i = 0; n0i < 8; n0i++)
            unsafeAtomicAdd(&wdst[n0i*16 + lane], colsum[n0i]);
    }
}

// beta = softmax over 2 of ((wsum/Na) . q)
__global__ void beta_kernel(const float* __restrict__ wsum, const float* __restrict__ q,
                            float* __restrict__ beta, float invN)
{
    __shared__ float r0s[128], r1s[128];
    const int tid = threadIdx.x;
    const float qv = q[tid];
    r0s[tid] = wsum[tid]     * invN * qv;
    r1s[tid] = wsum[128+tid] * invN * qv;
    __syncthreads();
    for (int st = 64; st > 0; st >>= 1){
        if (tid < st){ r0s[tid] += r0s[tid+st]; r1s[tid] += r1s[tid+st]; }
        __syncthreads();
    }
    if (tid == 0){
        const float w0 = r0s[0], w1 = r1s[0];
        const float m = fmaxf(w0, w1);
        const float e0 = __expf(w0-m), e1 = __expf(w1-m);
        const float inv = 1.f/(e0+e1);
        beta[0] = e0*inv; beta[1] = e1*inv;
    }
}

// sem = b0*relu(o_pa/s_pa) + b1*relu(o_da/s_da); logits=sem@Wl+bl; softmax
__global__ __launch_bounds__(256) void final_kernel(
    const float* __restrict__ o_pa, const float* __restrict__ o_da,
    const float* __restrict__ s_pa, const float* __restrict__ s_da,
    const float* __restrict__ beta,
    const float* __restrict__ Wl, const float* __restrict__ bl,
    float* __restrict__ out, int Na)
{
    const int gtid = blockIdx.x*256 + threadIdx.x;
    const int node = gtid >> 6;
    const int lane = threadIdx.x & 63;
    if (node >= Na) return;
    const float b0 = beta[0], b1 = beta[1];
    const size_t base = (size_t)node*128;
    const int hA = lane >> 4, hB = (lane+64) >> 4;
    const float ipA = 1.f/(s_pa[(size_t)node*8+hA]+1e-16f);
    const float ipB = 1.f/(s_pa[(size_t)node*8+hB]+1e-16f);
    const float idA = 1.f/(s_da[(size_t)node*8+hA]+1e-16f);
    const float idB = 1.f/(s_da[(size_t)node*8+hB]+1e-16f);
    const float pa0 = fmaxf(o_pa[base+lane]   *ipA, 0.f);
    const float pa1 = fmaxf(o_pa[base+64+lane]*ipB, 0.f);
    const float da0 = fmaxf(o_da[base+lane]   *idA, 0.f);
    const float da1 = fmaxf(o_da[base+64+lane]*idB, 0.f);
    const float sm0 = b0*pa0 + b1*da0;
    const float sm1 = b0*pa1 + b1*da1;
    const float w00 = Wl[lane*2+0],      w01 = Wl[lane*2+1];
    const float w10 = Wl[(lane+64)*2+0], w11 = Wl[(lane+64)*2+1];
    float l0 = sm0*w00 + sm1*w10;
    float l1 = sm0*w01 + sm1*w11;
    #pragma unroll
    for (int off = 32; off > 0; off >>= 1){
        l0 += __shfl_down(l0, off);
        l1 += __shfl_down(l1, off);
    }
    if (lane == 0){
        l0 += bl[0]; l1 += bl[1];
        const float m = fmaxf(l0, l1);
        const float e0 = __expf(l0-m), e1 = __expf(l1-m);
        const float inv = 1.f/(e0+e1);
        out[(size_t)node*2+0] = e0*inv;
        out[(size_t)node*2+1] = e1*inv;
    }
}

// ---------------------------------------------------------------------------
extern "C" void kernel_launch(void* const* d_in, const int* in_sizes, int n_in,
                              void* d_out, int out_size, void* d_ws, size_t ws_size,
                              hipStream_t stream)
{
    const float* x_adm    = (const float*)d_in[0];
    const float* x_pat    = (const float*)d_in[1];
    const float* x_diag   = (const float*)d_in[2];
    const int*   e_pa_src = (const int*)d_in[3];
    const int*   e_pa_dst = (const int*)d_in[4];
    const int*   e_da_src = (const int*)d_in[5];
    const int*   e_da_dst = (const int*)d_in[6];
    const float* Wa = (const float*)d_in[7];
    const float* ba = (const float*)d_in[8];
    const float* Wp = (const float*)d_in[9];
    const float* bp = (const float*)d_in[10];
    const float* Wd = (const float*)d_in[11];
    const float* bd = (const float*)d_in[12];
    const float* ats_pa = (const float*)d_in[13];
    const float* atd_pa = (const float*)d_in[14];
    const float* ats_da = (const float*)d_in[15];
    const float* atd_da = (const float*)d_in[16];
    const float* Wk = (const float*)d_in[17];
    const float* bk = (const float*)d_in[18];
    const float* q  = (const float*)d_in[19];
    const float* Wl = (const float*)d_in[20];
    const float* bl = (const float*)d_in[21];

    const int Na  = in_sizes[0] / 128;
    const int Np  = in_sizes[1] / 64;
    const int Nd  = in_sizes[2] / 64;
    const int Epa = in_sizes[3];
    const int Eda = in_sizes[5];

    float* ws = (float*)d_ws;
    size_t off = 0;
    // --- zero-initialized region (contiguous, one small memset) ---
    int*   cnt_pa = (int*)(ws + off); off += Na;   // histogram counts -> cursor
    int*   cnt_da = (int*)(ws + off); off += Na;
    float* wsum   = ws + off; off += 256;
    float* beta   = ws + off; off += 8;
    const size_t zero_len = off;
    // --- fully-overwritten region ---
    float* o_pa = ws + off; off += (size_t)Na*128;
    float* o_da = ws + off; off += (size_t)Na*128;
    float* s_pa = ws + off; off += (size_t)Na*8;
    float* s_da = ws + off; off += (size_t)Na*8;
    float* a_s_pa = ws + off; off += (size_t)Np*8;
    float* a_s_da = ws + off; off += (size_t)Nd*8;
    float* a_d_pa = ws + off; off += (size_t)Na*8;
    float* a_d_da = ws + off; off += (size_t)Na*8;
    float* Wf     = ws + off; off += 2048;
    float* bdot   = ws + off; off += 16;
    bf16*  h_p    = (bf16*)(ws + off); off += ((size_t)Np*128 + 1)/2;
    bf16*  h_d    = (bf16*)(ws + off); off += ((size_t)Nd*128 + 1)/2;
    int*   rowptr_pa = (int*)(ws + off); off += (size_t)Na + 1;
    int*   rowptr_da = (int*)(ws + off); off += (size_t)Na + 1;
    int*   sorted_pa = (int*)(ws + off); off += (size_t)Epa;
    int*   sorted_da = (int*)(ws + off); off += (size_t)Eda;
    int*   bsum_pa   = (int*)(ws + off); off += 256;
    int*   bsum_da   = (int*)(ws + off); off += 256;
    (void)n_in; (void)out_size; (void)ws_size; (void)off;

    hipMemsetAsync(d_ws, 0, zero_len*sizeof(float), stream);

    // fold attention into adm projection; thin GEMM for a_d (h_adm never built)
    prep_fold<<<1,128,0,stream>>>(Wa, ba, atd_pa, atd_da, Wf, bdot);
    {
        const int nt = (Na + 15)/16;
        afold_kernel<<<imin(nt,4096),256,0,stream>>>(x_adm, Wf, bdot,
                                                     a_d_pa, a_d_da, Na, nt);
    }
    // pat/diag projections (h stored bf16 + a_s dots)
    {
        const int nt = (Np + 31)/32;
        proj64<<<imin(nt,1024),256,0,stream>>>(x_pat, Wp, bp, ats_pa, h_p, a_s_pa, Np, nt);
    }
    {
        const int nt = (Nd + 31)/32;
        proj64<<<imin(nt,1024),256,0,stream>>>(x_diag, Wd, bd, ats_da, h_d, a_s_da, Nd, nt);
    }

    // --- counting sort of edges by dst (CSR) ---
    const int nbkt = (Na + 4095)/4096;
    hist_kernel<<<(Epa+255)/256, 256, 0, stream>>>(e_pa_dst, cnt_pa, Epa);
    hist_kernel<<<(Eda+255)/256, 256, 0, stream>>>(e_da_dst, cnt_da, Eda);
    scan_bsum<<<nbkt, 256, 0, stream>>>(cnt_pa, bsum_pa, Na);
    scan_bsum<<<nbkt, 256, 0, stream>>>(cnt_da, bsum_da, Na);
    scan_excl<<<1, 256, 0, stream>>>(bsum_pa, nbkt);
    scan_excl<<<1, 256, 0, stream>>>(bsum_da, nbkt);
    scan_write<<<nbkt, 256, 0, stream>>>(cnt_pa, bsum_pa, rowptr_pa, Na);
    scan_write<<<nbkt, 256, 0, stream>>>(cnt_da, bsum_da, rowptr_da, Na);
    scatter_kernel<<<(Epa+255)/256, 256, 0, stream>>>(e_pa_src, e_pa_dst, cnt_pa, sorted_pa, Epa);
    scatter_kernel<<<(Eda+255)/256, 256, 0, stream>>>(e_da_src, e_da_dst, cnt_da, sorted_da, Eda);

    // --- gather-aggregate (no atomics, single coalesced write of o/s) ---
    gather_kernel<<<(Na+3)/4, 256, 0, stream>>>(rowptr_pa, sorted_pa,
                                                a_s_pa, a_d_pa, h_p, s_pa, o_pa, Na);
    gather_kernel<<<(Na+3)/4, 256, 0, stream>>>(rowptr_da, sorted_da,
                                                a_s_da, a_d_da, h_d, s_da, o_da, Na);

    // semantic attention (MFMA; normalization fused into staging)
    {
        const int nt = (Na + 63)/64;
        dim3 grid(imin(nt,1024), 2);
        semw_mfma<<<grid, 256, 0, stream>>>(o_pa, o_da, s_pa, s_da, Wk, bk, wsum, Na, nt);
    }
    beta_kernel<<<1,128,0,stream>>>(wsum, q, beta, 1.f/(float)Na);

    // combine (normalization fused) + classifier + softmax
    final_kernel<<<(Na+3)/4, 256, 0, stream>>>(o_pa, o_da, s_pa, s_da, beta,
                                               Wl, bl, (float*)d_out, Na);
}

// Round 3
// 975.358 us; speedup vs baseline: 1.9433x; 1.2333x over previous
//
#include <hip/hip_runtime.h>
#include <hip/hip_bf16.h>

typedef __hip_bfloat16 bf16;
typedef __attribute__((ext_vector_type(8))) short frag_ab;   // 8 bf16
typedef __attribute__((ext_vector_type(4))) float frag_cd;   // 4 fp32

__device__ __forceinline__ short f2bs(float f){
    bf16 h = __float2bfloat16(f); short s; __builtin_memcpy(&s, &h, 2); return s;
}
__device__ __forceinline__ unsigned pack2(float a, float b){
    return (unsigned)(unsigned short)f2bs(a) | (((unsigned)(unsigned short)f2bs(b)) << 16);
}
__device__ __forceinline__ float blo(unsigned u){ return __uint_as_float(u << 16); }
__device__ __forceinline__ float bhi(unsigned u){ return __uint_as_float(u & 0xffff0000u); }
// tanh(x) = (e^{2x}-1)/(e^{2x}+1); |err| ~1e-6, feeds a 300K-node mean -> negligible
__device__ __forceinline__ float fast_tanh(float x){
    x = fminf(fmaxf(x, -15.f), 15.f);
    const float t = __expf(2.f*x);
    return (t - 1.f) * __builtin_amdgcn_rcpf(t + 1.f);
}
static inline int imin(int a, int b){ return a < b ? a : b; }

// ---------------------------------------------------------------------------
// Fold attention vectors into projection weights (a_d side for adm).
__global__ void prep_fold(const float* __restrict__ Wa, const float* __restrict__ ba,
                          const float* __restrict__ atd_pa, const float* __restrict__ atd_da,
                          float* __restrict__ Wf, float* __restrict__ bdot)
{
    const int k = threadIdx.x;  // 0..127
    for (int g = 0; g < 16; g++){
        const float* att = (g < 8) ? atd_pa : atd_da;
        const int h = g & 7;
        float ssum = 0.f;
        for (int d = 0; d < 16; d++)
            ssum += Wa[k*128 + h*16 + d] * att[h*16 + d];
        Wf[k*16 + g] = ssum;
    }
    if (k < 16){
        const float* att = (k < 8) ? atd_pa : atd_da;
        const int h = k & 7;
        float sb = 0.f;
        for (int d = 0; d < 16; d++) sb += ba[h*16 + d] * att[h*16 + d];
        bdot[k] = sb;
    }
}

// ---------------------------------------------------------------------------
// Thin GEMM: a_d[n,g] = x[n,:] @ Wf[:,g] + bdot[g]   (g<8 -> a_pa, else a_da)
__global__ __launch_bounds__(256) void afold_kernel(
    const float* __restrict__ x,     // [Na,128]
    const float* __restrict__ Wf,    // [128,16]
    const float* __restrict__ bdot,  // [16]
    float* __restrict__ a_pa,        // [Na,8]
    float* __restrict__ a_da,        // [Na,8]
    int Na, int ntiles)
{
    __shared__ float WfT[16*132];
    __shared__ float xsr[16*132];
    __shared__ float bs[16];
    const int tid = threadIdx.x;
    for (int i = tid; i < 2048; i += 256){
        const int k = i >> 4, g = i & 15;
        WfT[g*132 + k] = Wf[k*16 + g];
    }
    if (tid < 16) bs[tid] = bdot[tid];
    const int r = tid >> 4, g = tid & 15;

    for (int tile = blockIdx.x; tile < ntiles; tile += gridDim.x){
        const int row0 = tile*16;
        __syncthreads();
        for (int i = tid; i < 512; i += 256){
            const int rr = i >> 5, c4 = (i & 31)*4;
            const int row = row0 + rr;
            float4 v = make_float4(0.f,0.f,0.f,0.f);
            if (row < Na) v = *(const float4*)&x[(size_t)row*128 + c4];
            *(float4*)&xsr[rr*132 + c4] = v;
        }
        __syncthreads();
        float acc = bs[g];
        #pragma unroll 4
        for (int k0 = 0; k0 < 128; k0 += 4){
            const float4 xv = *(const float4*)&xsr[r*132 + k0];
            const float4 wv = *(const float4*)&WfT[g*132 + k0];
            acc += xv.x*wv.x + xv.y*wv.y + xv.z*wv.z + xv.w*wv.w;
        }
        const int row = row0 + r;
        if (row < Na){
            if (g < 8) a_pa[(size_t)row*8 + g]     = acc;
            else       a_da[(size_t)row*8 + (g-8)] = acc;
        }
    }
}

// ---------------------------------------------------------------------------
// Projection for pat/diag (K=64): h = x@W+b (stored bf16), a_s dots.
__global__ __launch_bounds__(256) void proj64(
    const float* __restrict__ x,      // [N,64]
    const float* __restrict__ W,      // [64,128]
    const float* __restrict__ b,      // [128]
    const float* __restrict__ att0,   // [128]
    bf16*  __restrict__ h_out,        // [N,128]
    float* __restrict__ a0_out,       // [N,8]
    int N, int ntiles)
{
    constexpr int K = 64;
    __shared__ float Wsf[K*128];
    __shared__ float xs[32*K];
    const int tid = threadIdx.x;
    const int cg = tid & 31;
    const int rg = tid >> 5;

    for (int i = tid; i < K*32; i += 256)
        *(float4*)&Wsf[i*4] = *(const float4*)&W[i*4];

    float bc[4], at0v[4];
    #pragma unroll
    for (int u = 0; u < 4; u++){ bc[u] = b[cg*4+u]; at0v[u] = att0[cg*4+u]; }
    const int head = cg >> 2;

    for (int tile = blockIdx.x; tile < ntiles; tile += gridDim.x){
        const int row0 = tile*32;
        __syncthreads();
        for (int i = tid; i < 32*(K/4); i += 256){
            const int r  = i / (K/4);
            const int c4 = (i % (K/4))*4;
            const int row = row0 + r;
            float4 v = make_float4(0.f,0.f,0.f,0.f);
            if (row < N) v = *(const float4*)&x[(size_t)row*K + c4];
            *(float4*)&xs[r*K + c4] = v;
        }
        __syncthreads();

        float acc[4][4];
        #pragma unroll
        for (int j = 0; j < 4; j++){ acc[j][0]=acc[j][1]=acc[j][2]=acc[j][3]=0.f; }

        #pragma unroll 2
        for (int k0 = 0; k0 < K; k0 += 4){
            float xr[4][4];
            #pragma unroll
            for (int j = 0; j < 4; j++){
                const float4 v = *(const float4*)&xs[(rg*4+j)*K + k0];
                xr[j][0]=v.x; xr[j][1]=v.y; xr[j][2]=v.z; xr[j][3]=v.w;
            }
            #pragma unroll
            for (int kk = 0; kk < 4; kk++){
                const float4 wv = *(const float4*)&Wsf[(k0+kk)*128 + cg*4];
                #pragma unroll
                for (int j = 0; j < 4; j++){
                    acc[j][0] = fmaf(xr[j][kk], wv.x, acc[j][0]);
                    acc[j][1] = fmaf(xr[j][kk], wv.y, acc[j][1]);
                    acc[j][2] = fmaf(xr[j][kk], wv.z, acc[j][2]);
                    acc[j][3] = fmaf(xr[j][kk], wv.w, acc[j][3]);
                }
            }
        }

        #pragma unroll
        for (int j = 0; j < 4; j++){
            const int row = row0 + rg*4 + j;
            const bool valid = row < N;
            const float h0 = acc[j][0]+bc[0], h1 = acc[j][1]+bc[1];
            const float h2 = acc[j][2]+bc[2], h3 = acc[j][3]+bc[3];
            if (valid){
                h_out[(size_t)row*128 + cg*4+0] = __float2bfloat16(h0);
                h_out[(size_t)row*128 + cg*4+1] = __float2bfloat16(h1);
                h_out[(size_t)row*128 + cg*4+2] = __float2bfloat16(h2);
                h_out[(size_t)row*128 + cg*4+3] = __float2bfloat16(h3);
            }
            float p0 = h0*at0v[0] + h1*at0v[1] + h2*at0v[2] + h3*at0v[3];
            p0 += __shfl_down(p0, 2, 4);
            p0 += __shfl_down(p0, 1, 4);
            if (valid && (cg & 3) == 0) a0_out[(size_t)row*8 + head] = p0;
        }
    }
}

// ---------------------------------------------------------------------------
// Counting sort of edges by destination -> CSR.
__global__ __launch_bounds__(256) void hist_kernel(
    const int* __restrict__ dst, int* __restrict__ cnt, int E)
{
    const int e = blockIdx.x*256 + threadIdx.x;
    if (e < E) atomicAdd(&cnt[dst[e]], 1);
}

__global__ __launch_bounds__(256) void scan_bsum(
    const int* __restrict__ cnt, int* __restrict__ bsum, int n)
{
    __shared__ int red[256];
    const int base = blockIdx.x*4096;
    int s = 0;
    for (int i = threadIdx.x; i < 4096; i += 256){
        const int idx = base + i;
        s += (idx < n) ? cnt[idx] : 0;
    }
    red[threadIdx.x] = s; __syncthreads();
    for (int st = 128; st > 0; st >>= 1){
        if (threadIdx.x < st) red[threadIdx.x] += red[threadIdx.x + st];
        __syncthreads();
    }
    if (threadIdx.x == 0) bsum[blockIdx.x] = red[0];
}

__global__ __launch_bounds__(256) void scan_excl(int* __restrict__ bsum, int nb)
{
    __shared__ int sh[256];
    const int t = threadIdx.x;
    sh[t] = (t < nb) ? bsum[t] : 0;
    __syncthreads();
    #pragma unroll
    for (int st = 1; st < 256; st <<= 1){
        const int u = (t >= st) ? sh[t - st] : 0;
        __syncthreads();
        sh[t] += u;
        __syncthreads();
    }
    if (t < nb) bsum[t] = t ? sh[t-1] : 0;
}

__global__ __launch_bounds__(256) void scan_write(
    int* __restrict__ cnt,            // in: counts; out: cursor (= rowptr copy)
    const int* __restrict__ bsum,
    int* __restrict__ rowptr, int n)
{
    __shared__ int sh[256];
    const int t = threadIdx.x;
    const int base = blockIdx.x*4096 + t*16;
    int loc[16]; int s = 0;
    #pragma unroll
    for (int i = 0; i < 16; i += 4){
        int4 v = make_int4(0,0,0,0);
        if (base + i + 3 < n) v = *(const int4*)&cnt[base + i];
        else {
            if (base+i   < n) v.x = cnt[base+i];
            if (base+i+1 < n) v.y = cnt[base+i+1];
            if (base+i+2 < n) v.z = cnt[base+i+2];
            if (base+i+3 < n) v.w = cnt[base+i+3];
        }
        loc[i]   = s; s += v.x;
        loc[i+1] = s; s += v.y;
        loc[i+2] = s; s += v.z;
        loc[i+3] = s; s += v.w;
    }
    sh[t] = s; __syncthreads();
    #pragma unroll
    for (int st = 1; st < 256; st <<= 1){
        const int u = (t >= st) ? sh[t - st] : 0;
        __syncthreads();
        sh[t] += u;
        __syncthreads();
    }
    const int off = bsum[blockIdx.x] + (t ? sh[t-1] : 0);
    #pragma unroll
    for (int i = 0; i < 16; i++){
        const int idx = base + i;
        if (idx < n){
            const int v = off + loc[i];
            rowptr[idx] = v;
            cnt[idx]    = v;   // cursor for scatter
        }
    }
    if (blockIdx.x == gridDim.x-1 && t == 255) rowptr[n] = off + s;
}

__global__ __launch_bounds__(256) void scatter_kernel(
    const int* __restrict__ src, const int* __restrict__ dst,
    int* __restrict__ cursor, int* __restrict__ sorted_src, int E)
{
    const int e = blockIdx.x*256 + threadIdx.x;
    if (e < E){
        const int pos = atomicAdd(&cursor[dst[e]], 1);
        sorted_src[pos] = src[e];
    }
}

// ---------------------------------------------------------------------------
// Gather-aggregate. One wave per dst node; lane l owns dims 2l,2l+1.
// Output: n_out = bf16(relu(o/ssum)) packed 2/dword — consumed by semw AND final.
// 4-deep software pipeline over edges for memory-level parallelism.
#define GATHER_EDGE(Ax, Hx) { \
    float lg = (Ax) + ad; \
    lg = lg >= 0.f ? lg : 0.2f*lg; \
    lg = fminf(fmaxf(lg, -30.f), 30.f); \
    const float ee = __expf(lg); \
    acc0 = fmaf(ee, blo(Hx), acc0); \
    acc1 = fmaf(ee, bhi(Hx), acc1); \
    ssum += ee; }

__global__ __launch_bounds__(256) void gather_kernel(
    const int* __restrict__ rowptr, const int* __restrict__ sorted_src,
    const float* __restrict__ a_s,    // [Ns,8]
    const float* __restrict__ a_d,    // [Na,8]
    const bf16*  __restrict__ h_src,  // [Ns,128]
    unsigned* __restrict__ n_out,     // [Na,64] dwords (2 bf16 each)
    int Na)
{
    const int n = blockIdx.x*4 + (threadIdx.x >> 6);
    if (n >= Na) return;
    const int l = threadIdx.x & 63;
    const int h = l >> 3;                       // head of dims 2l,2l+1
    const int beg = rowptr[n], end = rowptr[n+1];
    const float ad = a_d[(size_t)n*8 + h];
    const char* hb = (const char*)h_src;
    float acc0 = 0.f, acc1 = 0.f, ssum = 0.f;

    for (int base = beg; base < end; base += 64){
        const int nb = min(64, end - base);
        const int sv = sorted_src[min(base + l, end - 1)];
        for (int k = 0; k < nb; k += 4){
            const int r = nb - k;
            const int i0 = __shfl(sv, k);
            const int i1 = __shfl(sv, r > 1 ? k+1 : k);
            const int i2 = __shfl(sv, r > 2 ? k+2 : k);
            const int i3 = __shfl(sv, r > 3 ? k+3 : k);
            const float    A0 = a_s[(size_t)i0*8 + h];
            const unsigned H0 = *(const unsigned*)(hb + (size_t)i0*256 + l*4);
            const float    A1 = a_s[(size_t)i1*8 + h];
            const unsigned H1 = *(const unsigned*)(hb + (size_t)i1*256 + l*4);
            const float    A2 = a_s[(size_t)i2*8 + h];
            const unsigned H2 = *(const unsigned*)(hb + (size_t)i2*256 + l*4);
            const float    A3 = a_s[(size_t)i3*8 + h];
            const unsigned H3 = *(const unsigned*)(hb + (size_t)i3*256 + l*4);
            GATHER_EDGE(A0, H0)
            if (r > 1) GATHER_EDGE(A1, H1)
            if (r > 2) GATHER_EDGE(A2, H2)
            if (r > 3) GATHER_EDGE(A3, H3)
        }
    }
    const float inv = 1.f/(ssum + 1e-16f);
    n_out[(size_t)n*64 + l] = pack2(fmaxf(acc0*inv, 0.f), fmaxf(acc1*inv, 0.f));
}

// ---------------------------------------------------------------------------
// Semantic attention GEMM via bf16 MFMA 16x16x32 on pre-normalized bf16 n.
// 512 threads (8 waves), 128-row tiles; Wk staged coalesced into fragment LDS.
__global__ __launch_bounds__(512) void semw_mfma(
    const unsigned* __restrict__ np, const unsigned* __restrict__ nd,
    const float* __restrict__ Wk, const float* __restrict__ bk,
    float* __restrict__ wsum, int Na, int ntiles)
{
    __shared__ short Bs[4*8*64*8];     // [k0i][n0i][lane][j] bf16, 32 KB
    __shared__ short As[128*136];      // 128 rows x K=128 (stride 136), 34 KB
    const int tid  = threadIdx.x;
    const int lane = tid & 63;
    const int w    = tid >> 6;         // 0..7
    const int quad = lane >> 4;
    const int m16  = lane & 15;
    const unsigned* __restrict__ nn = blockIdx.y ? nd : np;

    // stage Wk -> B-fragment layout, COALESCED reads (float4 over rows)
    for (int f = tid; f < 4096; f += 512){
        const float4 v = *(const float4*)&Wk[f*4];
        const int k   = f >> 5;            // 32 float4 per 128-col row
        const int n4  = (f & 31)*4;
        const int k0i = k >> 5, kr = k & 31;
        const int lnb = (kr >> 3) << 4;
        const int j   = kr & 7;
        const float vv[4] = {v.x, v.y, v.z, v.w};
        #pragma unroll
        for (int t = 0; t < 4; t++){
            const int n = n4 + t;
            Bs[((k0i*8 + (n >> 4))*64 + (lnb | (n & 15)))*8 + j] = f2bs(vv[t]);
        }
    }

    float bkc[8];
    #pragma unroll
    for (int n0i = 0; n0i < 8; n0i++) bkc[n0i] = bk[n0i*16 + m16];

    float colsum[8] = {0.f,0.f,0.f,0.f,0.f,0.f,0.f,0.f};

    for (int tile = blockIdx.x; tile < ntiles; tile += gridDim.x){
        const int row0 = tile*128;
        __syncthreads();
        // stage 128 rows of n (straight 16B copies, values already relu'd bf16)
        for (int i = tid; i < 2048; i += 512){
            const int r = i >> 4, c16 = i & 15;
            const int row = row0 + r;
            uint4 u = make_uint4(0,0,0,0);
            if (row < Na) u = *(const uint4*)&nn[(size_t)row*64 + c16*4];
            *(uint4*)&As[r*136 + c16*8] = u;
        }
        __syncthreads();

        frag_cd acc[8];
        #pragma unroll
        for (int n0i = 0; n0i < 8; n0i++) acc[n0i] = (frag_cd){0.f,0.f,0.f,0.f};

        #pragma unroll
        for (int k0i = 0; k0i < 4; k0i++){
            frag_ab av = *(const frag_ab*)&As[(w*16 + m16)*136 + k0i*32 + quad*8];
            #pragma unroll
            for (int n0i = 0; n0i < 8; n0i++){
                frag_ab bv = *(const frag_ab*)&Bs[((k0i*8 + n0i)*64 + lane)*8];
                acc[n0i] = __builtin_amdgcn_mfma_f32_16x16x32_bf16(av, bv, acc[n0i], 0, 0, 0);
            }
        }

        // D: row = w*16 + quad*4 + reg, col = n0i*16 + m16. tanh then column-sum.
        #pragma unroll
        for (int n0i = 0; n0i < 8; n0i++){
            float part = 0.f;
            #pragma unroll
            for (int r = 0; r < 4; r++){
                const int row = row0 + w*16 + quad*4 + r;
                if (row < Na) part += fast_tanh(acc[n0i][r] + bkc[n0i]);
            }
            part += __shfl_down(part, 32);
            part += __shfl_down(part, 16);
            if (lane < 16) colsum[n0i] += part;
        }
    }
    if (lane < 16){
        float* wdst = wsum + blockIdx.y*128;
        #pragma unroll
        for (int n0i = 0; n0i < 8; n0i++)
            unsafeAtomicAdd(&wdst[n0i*16 + lane], colsum[n0i]);
    }
}

// beta = softmax over 2 of ((wsum/Na) . q)
__global__ void beta_kernel(const float* __restrict__ wsum, const float* __restrict__ q,
                            float* __restrict__ beta, float invN)
{
    __shared__ float r0s[128], r1s[128];
    const int tid = threadIdx.x;
    const float qv = q[tid];
    r0s[tid] = wsum[tid]     * invN * qv;
    r1s[tid] = wsum[128+tid] * invN * qv;
    __syncthreads();
    for (int st = 64; st > 0; st >>= 1){
        if (tid < st){ r0s[tid] += r0s[tid+st]; r1s[tid] += r1s[tid+st]; }
        __syncthreads();
    }
    if (tid == 0){
        const float w0 = r0s[0], w1 = r1s[0];
        const float m = fmaxf(w0, w1);
        const float e0 = __expf(w0-m), e1 = __expf(w1-m);
        const float inv = 1.f/(e0+e1);
        beta[0] = e0*inv; beta[1] = e1*inv;
    }
}

// sem = b0*n_pa + b1*n_da (bf16, already relu'd+normalized); logits=sem@Wl+bl; softmax
__global__ __launch_bounds__(256) void final_kernel(
    const unsigned* __restrict__ n_pa, const unsigned* __restrict__ n_da,
    const float* __restrict__ beta,
    const float* __restrict__ Wl, const float* __restrict__ bl,
    float* __restrict__ out, int Na)
{
    const int gtid = blockIdx.x*256 + threadIdx.x;
    const int node = gtid >> 6;
    const int lane = threadIdx.x & 63;
    if (node >= Na) return;
    const float b0 = beta[0], b1 = beta[1];
    const unsigned up = n_pa[(size_t)node*64 + lane];
    const unsigned ud = n_da[(size_t)node*64 + lane];
    const float sm0 = b0*blo(up) + b1*blo(ud);   // col 2*lane
    const float sm1 = b0*bhi(up) + b1*bhi(ud);   // col 2*lane+1
    const float4 wv = *(const float4*)&Wl[lane*4];  // rows 2l,2l+1 of Wl[128][2]
    float l0 = sm0*wv.x + sm1*wv.z;
    float l1 = sm0*wv.y + sm1*wv.w;
    #pragma unroll
    for (int off = 32; off > 0; off >>= 1){
        l0 += __shfl_down(l0, off);
        l1 += __shfl_down(l1, off);
    }
    if (lane == 0){
        l0 += bl[0]; l1 += bl[1];
        const float m = fmaxf(l0, l1);
        const float e0 = __expf(l0-m), e1 = __expf(l1-m);
        const float inv = 1.f/(e0+e1);
        out[(size_t)node*2+0] = e0*inv;
        out[(size_t)node*2+1] = e1*inv;
    }
}

// ---------------------------------------------------------------------------
extern "C" void kernel_launch(void* const* d_in, const int* in_sizes, int n_in,
                              void* d_out, int out_size, void* d_ws, size_t ws_size,
                              hipStream_t stream)
{
    const float* x_adm    = (const float*)d_in[0];
    const float* x_pat    = (const float*)d_in[1];
    const float* x_diag   = (const float*)d_in[2];
    const int*   e_pa_src = (const int*)d_in[3];
    const int*   e_pa_dst = (const int*)d_in[4];
    const int*   e_da_src = (const int*)d_in[5];
    const int*   e_da_dst = (const int*)d_in[6];
    const float* Wa = (const float*)d_in[7];
    const float* ba = (const float*)d_in[8];
    const float* Wp = (const float*)d_in[9];
    const float* bp = (const float*)d_in[10];
    const float* Wd = (const float*)d_in[11];
    const float* bd = (const float*)d_in[12];
    const float* ats_pa = (const float*)d_in[13];
    const float* atd_pa = (const float*)d_in[14];
    const float* ats_da = (const float*)d_in[15];
    const float* atd_da = (const float*)d_in[16];
    const float* Wk = (const float*)d_in[17];
    const float* bk = (const float*)d_in[18];
    const float* q  = (const float*)d_in[19];
    const float* Wl = (const float*)d_in[20];
    const float* bl = (const float*)d_in[21];

    const int Na  = in_sizes[0] / 128;
    const int Np  = in_sizes[1] / 64;
    const int Nd  = in_sizes[2] / 64;
    const int Epa = in_sizes[3];
    const int Eda = in_sizes[5];

    float* ws = (float*)d_ws;
    size_t off = 0;
    // --- zero-initialized region (contiguous, one small memset) ---
    int*   cnt_pa = (int*)(ws + off); off += Na;   // histogram counts -> cursor
    int*   cnt_da = (int*)(ws + off); off += Na;
    float* wsum   = ws + off; off += 256;
    float* beta   = ws + off; off += 8;
    const size_t zero_len = off;
    // --- fully-overwritten region ---
    off = (off + 3) & ~(size_t)3;                  // 16B align
    unsigned* n_pa = (unsigned*)(ws + off); off += (size_t)Na*64;  // [Na,64] dwords
    unsigned* n_da = (unsigned*)(ws + off); off += (size_t)Na*64;
    float* a_s_pa = ws + off; off += (size_t)Np*8;
    float* a_s_da = ws + off; off += (size_t)Nd*8;
    float* a_d_pa = ws + off; off += (size_t)Na*8;
    float* a_d_da = ws + off; off += (size_t)Na*8;
    float* Wf     = ws + off; off += 2048;
    float* bdot   = ws + off; off += 16;
    bf16*  h_p    = (bf16*)(ws + off); off += (size_t)Np*64;
    bf16*  h_d    = (bf16*)(ws + off); off += (size_t)Nd*64;
    int*   rowptr_pa = (int*)(ws + off); off += (size_t)Na + 1;
    int*   rowptr_da = (int*)(ws + off); off += (size_t)Na + 1;
    int*   sorted_pa = (int*)(ws + off); off += (size_t)Epa;
    int*   sorted_da = (int*)(ws + off); off += (size_t)Eda;
    int*   bsum_pa   = (int*)(ws + off); off += 256;
    int*   bsum_da   = (int*)(ws + off); off += 256;
    (void)n_in; (void)out_size; (void)ws_size; (void)off;

    hipMemsetAsync(d_ws, 0, zero_len*sizeof(float), stream);

    // fold attention into adm projection; thin GEMM for a_d (h_adm never built)
    prep_fold<<<1,128,0,stream>>>(Wa, ba, atd_pa, atd_da, Wf, bdot);
    {
        const int nt = (Na + 15)/16;
        afold_kernel<<<imin(nt,4096),256,0,stream>>>(x_adm, Wf, bdot,
                                                     a_d_pa, a_d_da, Na, nt);
    }
    // pat/diag projections (h stored bf16 + a_s dots)
    {
        const int nt = (Np + 31)/32;
        proj64<<<imin(nt,1024),256,0,stream>>>(x_pat, Wp, bp, ats_pa, h_p, a_s_pa, Np, nt);
    }
    {
        const int nt = (Nd + 31)/32;
        proj64<<<imin(nt,1024),256,0,stream>>>(x_diag, Wd, bd, ats_da, h_d, a_s_da, Nd, nt);
    }

    // --- counting sort of edges by dst (CSR) ---
    const int nbkt = (Na + 4095)/4096;
    hist_kernel<<<(Epa+255)/256, 256, 0, stream>>>(e_pa_dst, cnt_pa, Epa);
    hist_kernel<<<(Eda+255)/256, 256, 0, stream>>>(e_da_dst, cnt_da, Eda);
    scan_bsum<<<nbkt, 256, 0, stream>>>(cnt_pa, bsum_pa, Na);
    scan_bsum<<<nbkt, 256, 0, stream>>>(cnt_da, bsum_da, Na);
    scan_excl<<<1, 256, 0, stream>>>(bsum_pa, nbkt);
    scan_excl<<<1, 256, 0, stream>>>(bsum_da, nbkt);
    scan_write<<<nbkt, 256, 0, stream>>>(cnt_pa, bsum_pa, rowptr_pa, Na);
    scan_write<<<nbkt, 256, 0, stream>>>(cnt_da, bsum_da, rowptr_da, Na);
    scatter_kernel<<<(Epa+255)/256, 256, 0, stream>>>(e_pa_src, e_pa_dst, cnt_pa, sorted_pa, Epa);
    scatter_kernel<<<(Eda+255)/256, 256, 0, stream>>>(e_da_src, e_da_dst, cnt_da, sorted_da, Eda);

    // --- gather-aggregate -> normalized relu'd bf16 n arrays ---
    gather_kernel<<<(Na+3)/4, 256, 0, stream>>>(rowptr_pa, sorted_pa,
                                                a_s_pa, a_d_pa, h_p, n_pa, Na);
    gather_kernel<<<(Na+3)/4, 256, 0, stream>>>(rowptr_da, sorted_da,
                                                a_s_da, a_d_da, h_d, n_da, Na);

    // semantic attention (MFMA on bf16 n; 128-row tiles, 8 waves)
    {
        const int nt = (Na + 127)/128;
        dim3 grid(imin(nt, 256), 2);
        semw_mfma<<<grid, 512, 0, stream>>>(n_pa, n_da, Wk, bk, wsum, Na, nt);
    }
    beta_kernel<<<1,128,0,stream>>>(wsum, q, beta, 1.f/(float)Na);

    // combine + classifier + softmax (reads bf16 n arrays)
    final_kernel<<<(Na+3)/4, 256, 0, stream>>>(n_pa, n_da, beta,
                                               Wl, bl, (float*)d_out, Na);
}

// Round 5
// 936.631 us; speedup vs baseline: 2.0237x; 1.0413x over previous
//
#include <hip/hip_runtime.h>
#include <hip/hip_bf16.h>

typedef __hip_bfloat16 bf16;
typedef __attribute__((ext_vector_type(8))) short frag_ab;   // 8 bf16
typedef __attribute__((ext_vector_type(4))) float frag_cd;   // 4 fp32

__device__ __forceinline__ short f2bs(float f){
    bf16 h = __float2bfloat16(f); short s; __builtin_memcpy(&s, &h, 2); return s;
}
__device__ __forceinline__ unsigned pack2(float a, float b){
    return (unsigned)(unsigned short)f2bs(a) | (((unsigned)(unsigned short)f2bs(b)) << 16);
}
__device__ __forceinline__ float blo(unsigned u){ return __uint_as_float(u << 16); }
__device__ __forceinline__ float bhi(unsigned u){ return __uint_as_float(u & 0xffff0000u); }
// tanh(x) = (e^{2x}-1)/(e^{2x}+1); |err| ~1e-6, feeds a 300K-node mean -> negligible
__device__ __forceinline__ float fast_tanh(float x){
    x = fminf(fmaxf(x, -15.f), 15.f);
    const float t = __expf(2.f*x);
    return (t - 1.f) * __builtin_amdgcn_rcpf(t + 1.f);
}
static inline int imin(int a, int b){ return a < b ? a : b; }

// ---------------------------------------------------------------------------
// Fold attention vectors into projection weights (a_d side for adm).
__global__ void prep_fold(const float* __restrict__ Wa, const float* __restrict__ ba,
                          const float* __restrict__ atd_pa, const float* __restrict__ atd_da,
                          float* __restrict__ Wf, float* __restrict__ bdot)
{
    const int k = threadIdx.x;  // 0..127
    for (int g = 0; g < 16; g++){
        const float* att = (g < 8) ? atd_pa : atd_da;
        const int h = g & 7;
        float ssum = 0.f;
        for (int d = 0; d < 16; d++)
            ssum += Wa[k*128 + h*16 + d] * att[h*16 + d];
        Wf[k*16 + g] = ssum;
    }
    if (k < 16){
        const float* att = (k < 8) ? atd_pa : atd_da;
        const int h = k & 7;
        float sb = 0.f;
        for (int d = 0; d < 16; d++) sb += ba[h*16 + d] * att[h*16 + d];
        bdot[k] = sb;
    }
}

// ---------------------------------------------------------------------------
// Thin GEMM: a_d[n,g] = x[n,:] @ Wf[:,g] + bdot[g]   (g<8 -> a_pa, else a_da)
__global__ __launch_bounds__(256) void afold_kernel(
    const float* __restrict__ x,     // [Na,128]
    const float* __restrict__ Wf,    // [128,16]
    const float* __restrict__ bdot,  // [16]
    float* __restrict__ a_pa,        // [Na,8]
    float* __restrict__ a_da,        // [Na,8]
    int Na, int ntiles)
{
    __shared__ float WfT[16*132];
    __shared__ float xsr[16*132];
    __shared__ float bs[16];
    const int tid = threadIdx.x;
    for (int i = tid; i < 2048; i += 256){
        const int k = i >> 4, g = i & 15;
        WfT[g*132 + k] = Wf[k*16 + g];
    }
    if (tid < 16) bs[tid] = bdot[tid];
    const int r = tid >> 4, g = tid & 15;

    for (int tile = blockIdx.x; tile < ntiles; tile += gridDim.x){
        const int row0 = tile*16;
        __syncthreads();
        for (int i = tid; i < 512; i += 256){
            const int rr = i >> 5, c4 = (i & 31)*4;
            const int row = row0 + rr;
            float4 v = make_float4(0.f,0.f,0.f,0.f);
            if (row < Na) v = *(const float4*)&x[(size_t)row*128 + c4];
            *(float4*)&xsr[rr*132 + c4] = v;
        }
        __syncthreads();
        float acc = bs[g];
        #pragma unroll 4
        for (int k0 = 0; k0 < 128; k0 += 4){
            const float4 xv = *(const float4*)&xsr[r*132 + k0];
            const float4 wv = *(const float4*)&WfT[g*132 + k0];
            acc += xv.x*wv.x + xv.y*wv.y + xv.z*wv.z + xv.w*wv.w;
        }
        const int row = row0 + r;
        if (row < Na){
            if (g < 8) a_pa[(size_t)row*8 + g]     = acc;
            else       a_da[(size_t)row*8 + (g-8)] = acc;
        }
    }
}

// ---------------------------------------------------------------------------
// Projection for pat/diag (K=64): h = x@W+b (stored bf16), a_s dots.
__global__ __launch_bounds__(256) void proj64(
    const float* __restrict__ x,      // [N,64]
    const float* __restrict__ W,      // [64,128]
    const float* __restrict__ b,      // [128]
    const float* __restrict__ att0,   // [128]
    bf16*  __restrict__ h_out,        // [N,128]
    float* __restrict__ a0_out,       // [N,8]
    int N, int ntiles)
{
    constexpr int K = 64;
    __shared__ float Wsf[K*128];
    __shared__ float xs[32*K];
    const int tid = threadIdx.x;
    const int cg = tid & 31;
    const int rg = tid >> 5;

    for (int i = tid; i < K*32; i += 256)
        *(float4*)&Wsf[i*4] = *(const float4*)&W[i*4];

    float bc[4], at0v[4];
    #pragma unroll
    for (int u = 0; u < 4; u++){ bc[u] = b[cg*4+u]; at0v[u] = att0[cg*4+u]; }
    const int head = cg >> 2;

    for (int tile = blockIdx.x; tile < ntiles; tile += gridDim.x){
        const int row0 = tile*32;
        __syncthreads();
        for (int i = tid; i < 32*(K/4); i += 256){
            const int r  = i / (K/4);
            const int c4 = (i % (K/4))*4;
            const int row = row0 + r;
            float4 v = make_float4(0.f,0.f,0.f,0.f);
            if (row < N) v = *(const float4*)&x[(size_t)row*K + c4];
            *(float4*)&xs[r*K + c4] = v;
        }
        __syncthreads();

        float acc[4][4];
        #pragma unroll
        for (int j = 0; j < 4; j++){ acc[j][0]=acc[j][1]=acc[j][2]=acc[j][3]=0.f; }

        #pragma unroll 2
        for (int k0 = 0; k0 < K; k0 += 4){
            float xr[4][4];
            #pragma unroll
            for (int j = 0; j < 4; j++){
                const float4 v = *(const float4*)&xs[(rg*4+j)*K + k0];
                xr[j][0]=v.x; xr[j][1]=v.y; xr[j][2]=v.z; xr[j][3]=v.w;
            }
            #pragma unroll
            for (int kk = 0; kk < 4; kk++){
                const float4 wv = *(const float4*)&Wsf[(k0+kk)*128 + cg*4];
                #pragma unroll
                for (int j = 0; j < 4; j++){
                    acc[j][0] = fmaf(xr[j][kk], wv.x, acc[j][0]);
                    acc[j][1] = fmaf(xr[j][kk], wv.y, acc[j][1]);
                    acc[j][2] = fmaf(xr[j][kk], wv.z, acc[j][2]);
                    acc[j][3] = fmaf(xr[j][kk], wv.w, acc[j][3]);
                }
            }
        }

        #pragma unroll
        for (int j = 0; j < 4; j++){
            const int row = row0 + rg*4 + j;
            const bool valid = row < N;
            const float h0 = acc[j][0]+bc[0], h1 = acc[j][1]+bc[1];
            const float h2 = acc[j][2]+bc[2], h3 = acc[j][3]+bc[3];
            if (valid){
                h_out[(size_t)row*128 + cg*4+0] = __float2bfloat16(h0);
                h_out[(size_t)row*128 + cg*4+1] = __float2bfloat16(h1);
                h_out[(size_t)row*128 + cg*4+2] = __float2bfloat16(h2);
                h_out[(size_t)row*128 + cg*4+3] = __float2bfloat16(h3);
            }
            float p0 = h0*at0v[0] + h1*at0v[1] + h2*at0v[2] + h3*at0v[3];
            p0 += __shfl_down(p0, 2, 4);
            p0 += __shfl_down(p0, 1, 4);
            if (valid && (cg & 3) == 0) a0_out[(size_t)row*8 + head] = p0;
        }
    }
}

// ---------------------------------------------------------------------------
// Counting sort of edges by destination -> CSR.
__global__ __launch_bounds__(256) void hist_kernel(
    const int* __restrict__ dst, int* __restrict__ cnt, int E)
{
    const int e = blockIdx.x*256 + threadIdx.x;
    if (e < E) atomicAdd(&cnt[dst[e]], 1);
}

__global__ __launch_bounds__(256) void scan_bsum(
    const int* __restrict__ cnt, int* __restrict__ bsum, int n)
{
    __shared__ int red[256];
    const int base = blockIdx.x*4096;
    int s = 0;
    for (int i = threadIdx.x; i < 4096; i += 256){
        const int idx = base + i;
        s += (idx < n) ? cnt[idx] : 0;
    }
    red[threadIdx.x] = s; __syncthreads();
    for (int st = 128; st > 0; st >>= 1){
        if (threadIdx.x < st) red[threadIdx.x] += red[threadIdx.x + st];
        __syncthreads();
    }
    if (threadIdx.x == 0) bsum[blockIdx.x] = red[0];
}

__global__ __launch_bounds__(256) void scan_excl(int* __restrict__ bsum, int nb)
{
    __shared__ int sh[256];
    const int t = threadIdx.x;
    sh[t] = (t < nb) ? bsum[t] : 0;
    __syncthreads();
    #pragma unroll
    for (int st = 1; st < 256; st <<= 1){
        const int u = (t >= st) ? sh[t - st] : 0;
        __syncthreads();
        sh[t] += u;
        __syncthreads();
    }
    if (t < nb) bsum[t] = t ? sh[t-1] : 0;
}

__global__ __launch_bounds__(256) void scan_write(
    int* __restrict__ cnt,            // in: counts; out: cursor (= rowptr copy)
    const int* __restrict__ bsum,
    int* __restrict__ rowptr, int n)
{
    __shared__ int sh[256];
    const int t = threadIdx.x;
    const int base = blockIdx.x*4096 + t*16;
    int loc[16]; int s = 0;
    #pragma unroll
    for (int i = 0; i < 16; i += 4){
        int4 v = make_int4(0,0,0,0);
        if (base + i + 3 < n) v = *(const int4*)&cnt[base + i];
        else {
            if (base+i   < n) v.x = cnt[base+i];
            if (base+i+1 < n) v.y = cnt[base+i+1];
            if (base+i+2 < n) v.z = cnt[base+i+2];
            if (base+i+3 < n) v.w = cnt[base+i+3];
        }
        loc[i]   = s; s += v.x;
        loc[i+1] = s; s += v.y;
        loc[i+2] = s; s += v.z;
        loc[i+3] = s; s += v.w;
    }
    sh[t] = s; __syncthreads();
    #pragma unroll
    for (int st = 1; st < 256; st <<= 1){
        const int u = (t >= st) ? sh[t - st] : 0;
        __syncthreads();
        sh[t] += u;
        __syncthreads();
    }
    const int off = bsum[blockIdx.x] + (t ? sh[t-1] : 0);
    #pragma unroll
    for (int i = 0; i < 16; i++){
        const int idx = base + i;
        if (idx < n){
            const int v = off + loc[i];
            rowptr[idx] = v;
            cnt[idx]    = v;   // cursor for scatter
        }
    }
    if (blockIdx.x == gridDim.x-1 && t == 255) rowptr[n] = off + s;
}

__global__ __launch_bounds__(256) void scatter_kernel(
    const int* __restrict__ src, const int* __restrict__ dst,
    int* __restrict__ cursor, int* __restrict__ sorted_src, int E)
{
    const int e = blockIdx.x*256 + threadIdx.x;
    if (e < E){
        const int pos = atomicAdd(&cursor[dst[e]], 1);
        sorted_src[pos] = src[e];
    }
}

// ---------------------------------------------------------------------------
// Gather-aggregate. One wave per dst node; lane l owns dims 2l,2l+1.
// Output: n_out = bf16(relu(o/ssum)) packed 2/dword — consumed by semw AND final.
#define GATHER_EDGE(Ax, Hx) { \
    float lg = (Ax) + ad; \
    lg = lg >= 0.f ? lg : 0.2f*lg; \
    lg = fminf(fmaxf(lg, -30.f), 30.f); \
    const float ee = __expf(lg); \
    acc0 = fmaf(ee, blo(Hx), acc0); \
    acc1 = fmaf(ee, bhi(Hx), acc1); \
    ssum += ee; }

__global__ __launch_bounds__(256) void gather_kernel(
    const int* __restrict__ rowptr, const int* __restrict__ sorted_src,
    const float* __restrict__ a_s,    // [Ns,8]
    const float* __restrict__ a_d,    // [Na,8]
    const bf16*  __restrict__ h_src,  // [Ns,128]
    unsigned* __restrict__ n_out,     // [Na,64] dwords (2 bf16 each)
    int Na)
{
    const int n = blockIdx.x*4 + (threadIdx.x >> 6);
    if (n >= Na) return;
    const int l = threadIdx.x & 63;
    const int h = l >> 3;                       // head of dims 2l,2l+1
    const int beg = rowptr[n], end = rowptr[n+1];
    const float ad = a_d[(size_t)n*8 + h];
    const char* hb = (const char*)h_src;
    float acc0 = 0.f, acc1 = 0.f, ssum = 0.f;

    for (int base = beg; base < end; base += 64){
        const int nb = min(64, end - base);
        const int sv = sorted_src[min(base + l, end - 1)];
        for (int k = 0; k < nb; k += 4){
            const int r = nb - k;
            const int i0 = __shfl(sv, k);
            const int i1 = __shfl(sv, r > 1 ? k+1 : k);
            const int i2 = __shfl(sv, r > 2 ? k+2 : k);
            const int i3 = __shfl(sv, r > 3 ? k+3 : k);
            const float    A0 = a_s[(size_t)i0*8 + h];
            const unsigned H0 = *(const unsigned*)(hb + (size_t)i0*256 + l*4);
            const float    A1 = a_s[(size_t)i1*8 + h];
            const unsigned H1 = *(const unsigned*)(hb + (size_t)i1*256 + l*4);
            const float    A2 = a_s[(size_t)i2*8 + h];
            const unsigned H2 = *(const unsigned*)(hb + (size_t)i2*256 + l*4);
            const float    A3 = a_s[(size_t)i3*8 + h];
            const unsigned H3 = *(const unsigned*)(hb + (size_t)i3*256 + l*4);
            GATHER_EDGE(A0, H0)
            if (r > 1) GATHER_EDGE(A1, H1)
            if (r > 2) GATHER_EDGE(A2, H2)
            if (r > 3) GATHER_EDGE(A3, H3)
        }
    }
    const float inv = 1.f/(ssum + 1e-16f);
    n_out[(size_t)n*64 + l] = pack2(fmaxf(acc0*inv, 0.f), fmaxf(acc1*inv, 0.f));
}

// ---------------------------------------------------------------------------
// Semantic attention GEMM via bf16 MFMA 16x16x32 on pre-normalized bf16 n.
// n is ALREADY in A-fragment order in global memory: lane (quad,m16) loads
// 16B at nn[row*64 + k0i*16 + quad*4] -> NO As LDS, NO barriers in main loop.
// 256 threads (4 waves, 64 rows/tile), Bs (32KB) staged once, 1-tile prefetch.
#define SEMW_LOADA(dst, t) { \
    const int row_  = (t)*64 + w*16 + m16; \
    const size_t rb_ = (size_t)(row_ < Na ? row_ : Na-1)*64 + quad*4; \
    dst##0 = *(const frag_ab*)&nn[rb_]; \
    dst##1 = *(const frag_ab*)&nn[rb_ + 16]; \
    dst##2 = *(const frag_ab*)&nn[rb_ + 32]; \
    dst##3 = *(const frag_ab*)&nn[rb_ + 48]; }

__global__ __launch_bounds__(256) void semw_mfma(
    const unsigned* __restrict__ np, const unsigned* __restrict__ nd,
    const float* __restrict__ Wk, const float* __restrict__ bk,
    float* __restrict__ wsum, int Na, int nt)
{
    __shared__ short Bs[4*8*64*8];     // [k0i][n0i][lane][j] bf16, 32 KB
    __shared__ float csum[4][8][16];   // cross-wave reduce, 2 KB
    const int tid  = threadIdx.x;
    const int lane = tid & 63;
    const int w    = tid >> 6;         // 0..3
    const int quad = lane >> 4;
    const int m16  = lane & 15;
    const unsigned* __restrict__ nn = blockIdx.y ? nd : np;

    // stage Wk -> B-fragment layout, coalesced float4 reads
    for (int f = tid; f < 4096; f += 256){
        const float4 v = *(const float4*)&Wk[f*4];
        const int k   = f >> 5;            // 32 float4 per 128-col row
        const int n4  = (f & 31)*4;
        const int k0i = k >> 5, kr = k & 31;
        const int lnb = (kr >> 3) << 4;
        const int j   = kr & 7;
        const float vv[4] = {v.x, v.y, v.z, v.w};
        #pragma unroll
        for (int t = 0; t < 4; t++){
            const int n = n4 + t;
            Bs[((k0i*8 + (n >> 4))*64 + (lnb | (n & 15)))*8 + j] = f2bs(vv[t]);
        }
    }

    float bkc[8];
    #pragma unroll
    for (int n0i = 0; n0i < 8; n0i++) bkc[n0i] = bk[n0i*16 + m16];
    __syncthreads();

    float colsum[8] = {0.f,0.f,0.f,0.f,0.f,0.f,0.f,0.f};

    int tile = blockIdx.x;
    frag_ab a0 = {}, a1 = {}, a2 = {}, a3 = {};
    frag_ab p0 = {}, p1 = {}, p2 = {}, p3 = {};
    if (tile < nt) SEMW_LOADA(a, tile)
    while (tile < nt){
        const int tnext = tile + gridDim.x;
        if (tnext < nt) SEMW_LOADA(p, tnext)

        frag_cd acc[8];
        #pragma unroll
        for (int n0i = 0; n0i < 8; n0i++) acc[n0i] = (frag_cd){0.f,0.f,0.f,0.f};
        #pragma unroll
        for (int n0i = 0; n0i < 8; n0i++){
            acc[n0i] = __builtin_amdgcn_mfma_f32_16x16x32_bf16(a0,
                *(const frag_ab*)&Bs[((0*8 + n0i)*64 + lane)*8], acc[n0i], 0, 0, 0);
            acc[n0i] = __builtin_amdgcn_mfma_f32_16x16x32_bf16(a1,
                *(const frag_ab*)&Bs[((1*8 + n0i)*64 + lane)*8], acc[n0i], 0, 0, 0);
            acc[n0i] = __builtin_amdgcn_mfma_f32_16x16x32_bf16(a2,
                *(const frag_ab*)&Bs[((2*8 + n0i)*64 + lane)*8], acc[n0i], 0, 0, 0);
            acc[n0i] = __builtin_amdgcn_mfma_f32_16x16x32_bf16(a3,
                *(const frag_ab*)&Bs[((3*8 + n0i)*64 + lane)*8], acc[n0i], 0, 0, 0);
        }

        // D: row = tile*64 + w*16 + quad*4 + r, col = n0i*16 + m16
        const int row0 = tile*64 + w*16 + quad*4;
        #pragma unroll
        for (int n0i = 0; n0i < 8; n0i++){
            float part = 0.f;
            #pragma unroll
            for (int r = 0; r < 4; r++)
                if (row0 + r < Na) part += fast_tanh(acc[n0i][r] + bkc[n0i]);
            part += __shfl_down(part, 32);
            part += __shfl_down(part, 16);
            if (lane < 16) colsum[n0i] += part;
        }

        if (tnext < nt){ a0 = p0; a1 = p1; a2 = p2; a3 = p3; }
        tile = tnext;
    }

    // cross-wave reduce, then 128 atomics per block
    if (lane < 16){
        #pragma unroll
        for (int n0i = 0; n0i < 8; n0i++) csum[w][n0i][lane] = colsum[n0i];
    }
    __syncthreads();
    if (tid < 128){
        const int n0i = tid >> 4, l16 = tid & 15;
        const float v = csum[0][n0i][l16] + csum[1][n0i][l16]
                      + csum[2][n0i][l16] + csum[3][n0i][l16];
        unsafeAtomicAdd(&wsum[blockIdx.y*128 + n0i*16 + l16], v);
    }
}

// beta = softmax over 2 of ((wsum/Na) . q)
__global__ void beta_kernel(const float* __restrict__ wsum, const float* __restrict__ q,
                            float* __restrict__ beta, float invN)
{
    __shared__ float r0s[128], r1s[128];
    const int tid = threadIdx.x;
    const float qv = q[tid];
    r0s[tid] = wsum[tid]     * invN * qv;
    r1s[tid] = wsum[128+tid] * invN * qv;
    __syncthreads();
    for (int st = 64; st > 0; st >>= 1){
        if (tid < st){ r0s[tid] += r0s[tid+st]; r1s[tid] += r1s[tid+st]; }
        __syncthreads();
    }
    if (tid == 0){
        const float w0 = r0s[0], w1 = r1s[0];
        const float m = fmaxf(w0, w1);
        const float e0 = __expf(w0-m), e1 = __expf(w1-m);
        const float inv = 1.f/(e0+e1);
        beta[0] = e0*inv; beta[1] = e1*inv;
    }
}

// sem = b0*n_pa + b1*n_da (bf16, already relu'd+normalized); logits=sem@Wl+bl; softmax
__global__ __launch_bounds__(256) void final_kernel(
    const unsigned* __restrict__ n_pa, const unsigned* __restrict__ n_da,
    const float* __restrict__ beta,
    const float* __restrict__ Wl, const float* __restrict__ bl,
    float* __restrict__ out, int Na)
{
    const int gtid = blockIdx.x*256 + threadIdx.x;
    const int node = gtid >> 6;
    const int lane = threadIdx.x & 63;
    if (node >= Na) return;
    const float b0 = beta[0], b1 = beta[1];
    const unsigned up = n_pa[(size_t)node*64 + lane];
    const unsigned ud = n_da[(size_t)node*64 + lane];
    const float sm0 = b0*blo(up) + b1*blo(ud);   // col 2*lane
    const float sm1 = b0*bhi(up) + b1*bhi(ud);   // col 2*lane+1
    const float4 wv = *(const float4*)&Wl[lane*4];  // rows 2l,2l+1 of Wl[128][2]
    float l0 = sm0*wv.x + sm1*wv.z;
    float l1 = sm0*wv.y + sm1*wv.w;
    #pragma unroll
    for (int off = 32; off > 0; off >>= 1){
        l0 += __shfl_down(l0, off);
        l1 += __shfl_down(l1, off);
    }
    if (lane == 0){
        l0 += bl[0]; l1 += bl[1];
        const float m = fmaxf(l0, l1);
        const float e0 = __expf(l0-m), e1 = __expf(l1-m);
        const float inv = 1.f/(e0+e1);
        out[(size_t)node*2+0] = e0*inv;
        out[(size_t)node*2+1] = e1*inv;
    }
}

// ---------------------------------------------------------------------------
extern "C" void kernel_launch(void* const* d_in, const int* in_sizes, int n_in,
                              void* d_out, int out_size, void* d_ws, size_t ws_size,
                              hipStream_t stream)
{
    const float* x_adm    = (const float*)d_in[0];
    const float* x_pat    = (const float*)d_in[1];
    const float* x_diag   = (const float*)d_in[2];
    const int*   e_pa_src = (const int*)d_in[3];
    const int*   e_pa_dst = (const int*)d_in[4];
    const int*   e_da_src = (const int*)d_in[5];
    const int*   e_da_dst = (const int*)d_in[6];
    const float* Wa = (const float*)d_in[7];
    const float* ba = (const float*)d_in[8];
    const float* Wp = (const float*)d_in[9];
    const float* bp = (const float*)d_in[10];
    const float* Wd = (const float*)d_in[11];
    const float* bd = (const float*)d_in[12];
    const float* ats_pa = (const float*)d_in[13];
    const float* atd_pa = (const float*)d_in[14];
    const float* ats_da = (const float*)d_in[15];
    const float* atd_da = (const float*)d_in[16];
    const float* Wk = (const float*)d_in[17];
    const float* bk = (const float*)d_in[18];
    const float* q  = (const float*)d_in[19];
    const float* Wl = (const float*)d_in[20];
    const float* bl = (const float*)d_in[21];

    const int Na  = in_sizes[0] / 128;
    const int Np  = in_sizes[1] / 64;
    const int Nd  = in_sizes[2] / 64;
    const int Epa = in_sizes[3];
    const int Eda = in_sizes[5];

    float* ws = (float*)d_ws;
    size_t off = 0;
    // --- zero-initialized region (contiguous, one small memset) ---
    int*   cnt_pa = (int*)(ws + off); off += Na;   // histogram counts -> cursor
    int*   cnt_da = (int*)(ws + off); off += Na;
    float* wsum   = ws + off; off += 256;
    float* beta   = ws + off; off += 8;
    const size_t zero_len = off;
    // --- fully-overwritten region ---
    off = (off + 3) & ~(size_t)3;                  // 16B align
    unsigned* n_pa = (unsigned*)(ws + off); off += (size_t)Na*64;  // [Na,64] dwords
    unsigned* n_da = (unsigned*)(ws + off); off += (size_t)Na*64;
    float* a_s_pa = ws + off; off += (size_t)Np*8;
    float* a_s_da = ws + off; off += (size_t)Nd*8;
    float* a_d_pa = ws + off; off += (size_t)Na*8;
    float* a_d_da = ws + off; off += (size_t)Na*8;
    float* Wf     = ws + off; off += 2048;
    float* bdot   = ws + off; off += 16;
    bf16*  h_p    = (bf16*)(ws + off); off += (size_t)Np*64;
    bf16*  h_d    = (bf16*)(ws + off); off += (size_t)Nd*64;
    int*   rowptr_pa = (int*)(ws + off); off += (size_t)Na + 1;
    int*   rowptr_da = (int*)(ws + off); off += (size_t)Na + 1;
    int*   sorted_pa = (int*)(ws + off); off += (size_t)Epa;
    int*   sorted_da = (int*)(ws + off); off += (size_t)Eda;
    int*   bsum_pa   = (int*)(ws + off); off += 256;
    int*   bsum_da   = (int*)(ws + off); off += 256;
    (void)n_in; (void)out_size; (void)ws_size; (void)off;

    hipMemsetAsync(d_ws, 0, zero_len*sizeof(float), stream);

    // fold attention into adm projection; thin GEMM for a_d (h_adm never built)
    prep_fold<<<1,128,0,stream>>>(Wa, ba, atd_pa, atd_da, Wf, bdot);
    {
        const int nt = (Na + 15)/16;
        afold_kernel<<<imin(nt,4096),256,0,stream>>>(x_adm, Wf, bdot,
                                                     a_d_pa, a_d_da, Na, nt);
    }
    // pat/diag projections (h stored bf16 + a_s dots)
    {
        const int nt = (Np + 31)/32;
        proj64<<<imin(nt,1024),256,0,stream>>>(x_pat, Wp, bp, ats_pa, h_p, a_s_pa, Np, nt);
    }
    {
        const int nt = (Nd + 31)/32;
        proj64<<<imin(nt,1024),256,0,stream>>>(x_diag, Wd, bd, ats_da, h_d, a_s_da, Nd, nt);
    }

    // --- counting sort of edges by dst (CSR) ---
    const int nbkt = (Na + 4095)/4096;
    hist_kernel<<<(Epa+255)/256, 256, 0, stream>>>(e_pa_dst, cnt_pa, Epa);
    hist_kernel<<<(Eda+255)/256, 256, 0, stream>>>(e_da_dst, cnt_da, Eda);
    scan_bsum<<<nbkt, 256, 0, stream>>>(cnt_pa, bsum_pa, Na);
    scan_bsum<<<nbkt, 256, 0, stream>>>(cnt_da, bsum_da, Na);
    scan_excl<<<1, 256, 0, stream>>>(bsum_pa, nbkt);
    scan_excl<<<1, 256, 0, stream>>>(bsum_da, nbkt);
    scan_write<<<nbkt, 256, 0, stream>>>(cnt_pa, bsum_pa, rowptr_pa, Na);
    scan_write<<<nbkt, 256, 0, stream>>>(cnt_da, bsum_da, rowptr_da, Na);
    scatter_kernel<<<(Epa+255)/256, 256, 0, stream>>>(e_pa_src, e_pa_dst, cnt_pa, sorted_pa, Epa);
    scatter_kernel<<<(Eda+255)/256, 256, 0, stream>>>(e_da_src, e_da_dst, cnt_da, sorted_da, Eda);

    // --- gather-aggregate -> normalized relu'd bf16 n arrays ---
    gather_kernel<<<(Na+3)/4, 256, 0, stream>>>(rowptr_pa, sorted_pa,
                                                a_s_pa, a_d_pa, h_p, n_pa, Na);
    gather_kernel<<<(Na+3)/4, 256, 0, stream>>>(rowptr_da, sorted_da,
                                                a_s_da, a_d_da, h_d, n_da, Na);

    // semantic attention (MFMA on bf16 n; barrier-free main loop, A from global)
    {
        const int nt = (Na + 63)/64;
        dim3 grid(imin(nt, 512), 2);
        semw_mfma<<<grid, 256, 0, stream>>>(n_pa, n_da, Wk, bk, wsum, Na, nt);
    }
    beta_kernel<<<1,128,0,stream>>>(wsum, q, beta, 1.f/(float)Na);

    // combine + classifier + softmax (reads bf16 n arrays)
    final_kernel<<<(Na+3)/4, 256, 0, stream>>>(n_pa, n_da, beta,
                                               Wl, bl, (float*)d_out, Na);
}

// Round 6
// 877.268 us; speedup vs baseline: 2.1606x; 1.0677x over previous
//
#include <hip/hip_runtime.h>
#include <hip/hip_bf16.h>

typedef __hip_bfloat16 bf16;
typedef __attribute__((ext_vector_type(8))) short frag_ab;   // 8 bf16
typedef __attribute__((ext_vector_type(4))) float frag_cd;   // 4 fp32

__device__ __forceinline__ short f2bs(float f){
    bf16 h = __float2bfloat16(f); short s; __builtin_memcpy(&s, &h, 2); return s;
}
__device__ __forceinline__ unsigned pack2(float a, float b){
    return (unsigned)(unsigned short)f2bs(a) | (((unsigned)(unsigned short)f2bs(b)) << 16);
}
__device__ __forceinline__ float blo(unsigned u){ return __uint_as_float(u << 16); }
__device__ __forceinline__ float bhi(unsigned u){ return __uint_as_float(u & 0xffff0000u); }
// tanh(x) = (e^{2x}-1)/(e^{2x}+1); |err| ~1e-6, feeds a 300K-node mean -> negligible
__device__ __forceinline__ float fast_tanh(float x){
    x = fminf(fmaxf(x, -15.f), 15.f);
    const float t = __expf(2.f*x);
    return (t - 1.f) * __builtin_amdgcn_rcpf(t + 1.f);
}
static inline int imin(int a, int b){ return a < b ? a : b; }

// ---------------------------------------------------------------------------
// Fold attention vectors into projection weights (a_d side for adm).
__global__ void prep_fold(const float* __restrict__ Wa, const float* __restrict__ ba,
                          const float* __restrict__ atd_pa, const float* __restrict__ atd_da,
                          float* __restrict__ Wf, float* __restrict__ bdot)
{
    const int k = threadIdx.x;  // 0..127
    for (int g = 0; g < 16; g++){
        const float* att = (g < 8) ? atd_pa : atd_da;
        const int h = g & 7;
        float ssum = 0.f;
        for (int d = 0; d < 16; d++)
            ssum += Wa[k*128 + h*16 + d] * att[h*16 + d];
        Wf[k*16 + g] = ssum;
    }
    if (k < 16){
        const float* att = (k < 8) ? atd_pa : atd_da;
        const int h = k & 7;
        float sb = 0.f;
        for (int d = 0; d < 16; d++) sb += ba[h*16 + d] * att[h*16 + d];
        bdot[k] = sb;
    }
}

// ---------------------------------------------------------------------------
// Thin GEMM: a_d[n,g] = x[n,:] @ Wf[:,g] + bdot[g]   (g<8 -> a_pa, else a_da)
__global__ __launch_bounds__(256) void afold_kernel(
    const float* __restrict__ x,     // [Na,128]
    const float* __restrict__ Wf,    // [128,16]
    const float* __restrict__ bdot,  // [16]
    float* __restrict__ a_pa,        // [Na,8]
    float* __restrict__ a_da,        // [Na,8]
    int Na, int ntiles)
{
    __shared__ float WfT[16*132];
    __shared__ float xsr[16*132];
    __shared__ float bs[16];
    const int tid = threadIdx.x;
    for (int i = tid; i < 2048; i += 256){
        const int k = i >> 4, g = i & 15;
        WfT[g*132 + k] = Wf[k*16 + g];
    }
    if (tid < 16) bs[tid] = bdot[tid];
    const int r = tid >> 4, g = tid & 15;

    for (int tile = blockIdx.x; tile < ntiles; tile += gridDim.x){
        const int row0 = tile*16;
        __syncthreads();
        for (int i = tid; i < 512; i += 256){
            const int rr = i >> 5, c4 = (i & 31)*4;
            const int row = row0 + rr;
            float4 v = make_float4(0.f,0.f,0.f,0.f);
            if (row < Na) v = *(const float4*)&x[(size_t)row*128 + c4];
            *(float4*)&xsr[rr*132 + c4] = v;
        }
        __syncthreads();
        float acc = bs[g];
        #pragma unroll 4
        for (int k0 = 0; k0 < 128; k0 += 4){
            const float4 xv = *(const float4*)&xsr[r*132 + k0];
            const float4 wv = *(const float4*)&WfT[g*132 + k0];
            acc += xv.x*wv.x + xv.y*wv.y + xv.z*wv.z + xv.w*wv.w;
        }
        const int row = row0 + r;
        if (row < Na){
            if (g < 8) a_pa[(size_t)row*8 + g]     = acc;
            else       a_da[(size_t)row*8 + (g-8)] = acc;
        }
    }
}

// ---------------------------------------------------------------------------
// Projection for pat/diag (K=64): h = x@W+b (stored bf16), a_s dots.
__global__ __launch_bounds__(256) void proj64(
    const float* __restrict__ x,      // [N,64]
    const float* __restrict__ W,      // [64,128]
    const float* __restrict__ b,      // [128]
    const float* __restrict__ att0,   // [128]
    bf16*  __restrict__ h_out,        // [N,128]
    float* __restrict__ a0_out,       // [N,8]
    int N, int ntiles)
{
    constexpr int K = 64;
    __shared__ float Wsf[K*128];
    __shared__ float xs[32*K];
    const int tid = threadIdx.x;
    const int cg = tid & 31;
    const int rg = tid >> 5;

    for (int i = tid; i < K*32; i += 256)
        *(float4*)&Wsf[i*4] = *(const float4*)&W[i*4];

    float bc[4], at0v[4];
    #pragma unroll
    for (int u = 0; u < 4; u++){ bc[u] = b[cg*4+u]; at0v[u] = att0[cg*4+u]; }
    const int head = cg >> 2;

    for (int tile = blockIdx.x; tile < ntiles; tile += gridDim.x){
        const int row0 = tile*32;
        __syncthreads();
        for (int i = tid; i < 32*(K/4); i += 256){
            const int r  = i / (K/4);
            const int c4 = (i % (K/4))*4;
            const int row = row0 + r;
            float4 v = make_float4(0.f,0.f,0.f,0.f);
            if (row < N) v = *(const float4*)&x[(size_t)row*K + c4];
            *(float4*)&xs[r*K + c4] = v;
        }
        __syncthreads();

        float acc[4][4];
        #pragma unroll
        for (int j = 0; j < 4; j++){ acc[j][0]=acc[j][1]=acc[j][2]=acc[j][3]=0.f; }

        #pragma unroll 2
        for (int k0 = 0; k0 < K; k0 += 4){
            float xr[4][4];
            #pragma unroll
            for (int j = 0; j < 4; j++){
                const float4 v = *(const float4*)&xs[(rg*4+j)*K + k0];
                xr[j][0]=v.x; xr[j][1]=v.y; xr[j][2]=v.z; xr[j][3]=v.w;
            }
            #pragma unroll
            for (int kk = 0; kk < 4; kk++){
                const float4 wv = *(const float4*)&Wsf[(k0+kk)*128 + cg*4];
                #pragma unroll
                for (int j = 0; j < 4; j++){
                    acc[j][0] = fmaf(xr[j][kk], wv.x, acc[j][0]);
                    acc[j][1] = fmaf(xr[j][kk], wv.y, acc[j][1]);
                    acc[j][2] = fmaf(xr[j][kk], wv.z, acc[j][2]);
                    acc[j][3] = fmaf(xr[j][kk], wv.w, acc[j][3]);
                }
            }
        }

        #pragma unroll
        for (int j = 0; j < 4; j++){
            const int row = row0 + rg*4 + j;
            const bool valid = row < N;
            const float h0 = acc[j][0]+bc[0], h1 = acc[j][1]+bc[1];
            const float h2 = acc[j][2]+bc[2], h3 = acc[j][3]+bc[3];
            if (valid){
                h_out[(size_t)row*128 + cg*4+0] = __float2bfloat16(h0);
                h_out[(size_t)row*128 + cg*4+1] = __float2bfloat16(h1);
                h_out[(size_t)row*128 + cg*4+2] = __float2bfloat16(h2);
                h_out[(size_t)row*128 + cg*4+3] = __float2bfloat16(h3);
            }
            float p0 = h0*at0v[0] + h1*at0v[1] + h2*at0v[2] + h3*at0v[3];
            p0 += __shfl_down(p0, 2, 4);
            p0 += __shfl_down(p0, 1, 4);
            if (valid && (cg & 3) == 0) a0_out[(size_t)row*8 + head] = p0;
        }
    }
}

// ---------------------------------------------------------------------------
// Counting sort of edges by destination -> CSR.
__global__ __launch_bounds__(256) void hist_kernel(
    const int* __restrict__ dst, int* __restrict__ cnt, int E)
{
    const int e = blockIdx.x*256 + threadIdx.x;
    if (e < E) atomicAdd(&cnt[dst[e]], 1);
}

__global__ __launch_bounds__(256) void scan_bsum(
    const int* __restrict__ cnt, int* __restrict__ bsum, int n)
{
    __shared__ int red[256];
    const int base = blockIdx.x*4096;
    int s = 0;
    for (int i = threadIdx.x; i < 4096; i += 256){
        const int idx = base + i;
        s += (idx < n) ? cnt[idx] : 0;
    }
    red[threadIdx.x] = s; __syncthreads();
    for (int st = 128; st > 0; st >>= 1){
        if (threadIdx.x < st) red[threadIdx.x] += red[threadIdx.x + st];
        __syncthreads();
    }
    if (threadIdx.x == 0) bsum[blockIdx.x] = red[0];
}

__global__ __launch_bounds__(256) void scan_excl(int* __restrict__ bsum, int nb)
{
    __shared__ int sh[256];
    const int t = threadIdx.x;
    sh[t] = (t < nb) ? bsum[t] : 0;
    __syncthreads();
    #pragma unroll
    for (int st = 1; st < 256; st <<= 1){
        const int u = (t >= st) ? sh[t - st] : 0;
        __syncthreads();
        sh[t] += u;
        __syncthreads();
    }
    if (t < nb) bsum[t] = t ? sh[t-1] : 0;
}

__global__ __launch_bounds__(256) void scan_write(
    int* __restrict__ cnt,            // in: counts; out: cursor (= rowptr copy)
    const int* __restrict__ bsum,
    int* __restrict__ rowptr, int n)
{
    __shared__ int sh[256];
    const int t = threadIdx.x;
    const int base = blockIdx.x*4096 + t*16;
    int loc[16]; int s = 0;
    #pragma unroll
    for (int i = 0; i < 16; i += 4){
        int4 v = make_int4(0,0,0,0);
        if (base + i + 3 < n) v = *(const int4*)&cnt[base + i];
        else {
            if (base+i   < n) v.x = cnt[base+i];
            if (base+i+1 < n) v.y = cnt[base+i+1];
            if (base+i+2 < n) v.z = cnt[base+i+2];
            if (base+i+3 < n) v.w = cnt[base+i+3];
        }
        loc[i]   = s; s += v.x;
        loc[i+1] = s; s += v.y;
        loc[i+2] = s; s += v.z;
        loc[i+3] = s; s += v.w;
    }
    sh[t] = s; __syncthreads();
    #pragma unroll
    for (int st = 1; st < 256; st <<= 1){
        const int u = (t >= st) ? sh[t - st] : 0;
        __syncthreads();
        sh[t] += u;
        __syncthreads();
    }
    const int off = bsum[blockIdx.x] + (t ? sh[t-1] : 0);
    #pragma unroll
    for (int i = 0; i < 16; i++){
        const int idx = base + i;
        if (idx < n){
            const int v = off + loc[i];
            rowptr[idx] = v;
            cnt[idx]    = v;   // cursor for scatter
        }
    }
    if (blockIdx.x == gridDim.x-1 && t == 255) rowptr[n] = off + s;
}

__global__ __launch_bounds__(256) void scatter_kernel(
    const int* __restrict__ src, const int* __restrict__ dst,
    int* __restrict__ cursor, int* __restrict__ sorted_src, int E)
{
    const int e = blockIdx.x*256 + threadIdx.x;
    if (e < E){
        const int pos = atomicAdd(&cursor[dst[e]], 1);
        sorted_src[pos] = src[e];
    }
}

// ---------------------------------------------------------------------------
// Gather-aggregate, 16 lanes per dst node (4 nodes/wave, 16 nodes/block).
// Lane l owns dims 8l..8l+7 (one uint4 = full 256B row per 16-lane group).
// Both edge types in one launch (group id >= Na -> da). Edge order per node
// identical to before -> bit-identical results.
#define GEDGE(Ax, Hx) { \
    float lg = (Ax) + ad; \
    lg = lg >= 0.f ? lg : 0.2f*lg; \
    lg = fminf(fmaxf(lg, -30.f), 30.f); \
    const float ee = __expf(lg); \
    acc0 = fmaf(ee, blo(Hx.x), acc0); acc1 = fmaf(ee, bhi(Hx.x), acc1); \
    acc2 = fmaf(ee, blo(Hx.y), acc2); acc3 = fmaf(ee, bhi(Hx.y), acc3); \
    acc4 = fmaf(ee, blo(Hx.z), acc4); acc5 = fmaf(ee, bhi(Hx.z), acc5); \
    acc6 = fmaf(ee, blo(Hx.w), acc6); acc7 = fmaf(ee, bhi(Hx.w), acc7); \
    ssum += ee; }

__global__ __launch_bounds__(256) void gather_kernel(
    const int* __restrict__ rowptr0, const int* __restrict__ sorted0,
    const float* __restrict__ as0, const float* __restrict__ ad0,
    const bf16* __restrict__ h0, unsigned* __restrict__ nout0,
    const int* __restrict__ rowptr1, const int* __restrict__ sorted1,
    const float* __restrict__ as1, const float* __restrict__ ad1,
    const bf16* __restrict__ h1, unsigned* __restrict__ nout1,
    int Na)
{
    const int gid = blockIdx.x*16 + (threadIdx.x >> 4);
    const int l   = threadIdx.x & 15;
    if (gid >= 2*Na) return;
    const bool ty = gid >= Na;
    const int n = ty ? gid - Na : gid;
    const int*   rowptr = ty ? rowptr1 : rowptr0;
    const int*   sorted = ty ? sorted1 : sorted0;
    const float* a_s    = ty ? as1 : as0;
    const char*  hb     = (const char*)(ty ? h1 : h0);
    unsigned*    nout   = ty ? nout1 : nout0;
    const int hh  = l >> 1;                       // head of dims 8l..8l+7
    const float ad = (ty ? ad1 : ad0)[(size_t)n*8 + hh];

    const int beg = rowptr[n], end = rowptr[n+1];
    float acc0=0.f,acc1=0.f,acc2=0.f,acc3=0.f,acc4=0.f,acc5=0.f,acc6=0.f,acc7=0.f;
    float ssum=0.f;

    for (int base = beg; base < end; base += 16){
        const int nb = min(16, end - base);
        const int sv = sorted[min(base + l, end - 1)];
        for (int k = 0; k < nb; k += 2){
            const int i0 = __shfl(sv, k, 16);
            const int i1 = __shfl(sv, (k+1 < nb) ? k+1 : k, 16);
            const float A0 = a_s[(size_t)i0*8 + hh];
            const uint4 H0 = *(const uint4*)(hb + (size_t)i0*256 + l*16);
            const float A1 = a_s[(size_t)i1*8 + hh];
            const uint4 H1 = *(const uint4*)(hb + (size_t)i1*256 + l*16);
            GEDGE(A0, H0)
            if (k+1 < nb) GEDGE(A1, H1)
        }
    }
    const float inv = 1.f/(ssum + 1e-16f);
    uint4 u;
    u.x = pack2(fmaxf(acc0*inv,0.f), fmaxf(acc1*inv,0.f));
    u.y = pack2(fmaxf(acc2*inv,0.f), fmaxf(acc3*inv,0.f));
    u.z = pack2(fmaxf(acc4*inv,0.f), fmaxf(acc5*inv,0.f));
    u.w = pack2(fmaxf(acc6*inv,0.f), fmaxf(acc7*inv,0.f));
    *(uint4*)&nout[(size_t)n*64 + l*4] = u;
}

// ---------------------------------------------------------------------------
// Semantic attention GEMM via bf16 MFMA 16x16x32 on pre-normalized bf16 n.
// n is ALREADY in A-fragment order in global memory: lane (quad,m16) loads
// 16B at nn[row*64 + k0i*16 + quad*4] -> NO As LDS, NO barriers in main loop.
// 256 threads (4 waves, 64 rows/tile), Bs (32KB) staged once, 1-tile prefetch.
#define SEMW_LOADA(dst, t) { \
    const int row_  = (t)*64 + w*16 + m16; \
    const size_t rb_ = (size_t)(row_ < Na ? row_ : Na-1)*64 + quad*4; \
    dst##0 = *(const frag_ab*)&nn[rb_]; \
    dst##1 = *(const frag_ab*)&nn[rb_ + 16]; \
    dst##2 = *(const frag_ab*)&nn[rb_ + 32]; \
    dst##3 = *(const frag_ab*)&nn[rb_ + 48]; }

__global__ __launch_bounds__(256) void semw_mfma(
    const unsigned* __restrict__ np, const unsigned* __restrict__ nd,
    const float* __restrict__ Wk, const float* __restrict__ bk,
    float* __restrict__ wsum, int Na, int nt)
{
    __shared__ short Bs[4*8*64*8];     // [k0i][n0i][lane][j] bf16, 32 KB
    __shared__ float csum[4][8][16];   // cross-wave reduce, 2 KB
    const int tid  = threadIdx.x;
    const int lane = tid & 63;
    const int w    = tid >> 6;         // 0..3
    const int quad = lane >> 4;
    const int m16  = lane & 15;
    const unsigned* __restrict__ nn = blockIdx.y ? nd : np;

    // stage Wk -> B-fragment layout, coalesced float4 reads
    for (int f = tid; f < 4096; f += 256){
        const float4 v = *(const float4*)&Wk[f*4];
        const int k   = f >> 5;            // 32 float4 per 128-col row
        const int n4  = (f & 31)*4;
        const int k0i = k >> 5, kr = k & 31;
        const int lnb = (kr >> 3) << 4;
        const int j   = kr & 7;
        const float vv[4] = {v.x, v.y, v.z, v.w};
        #pragma unroll
        for (int t = 0; t < 4; t++){
            const int n = n4 + t;
            Bs[((k0i*8 + (n >> 4))*64 + (lnb | (n & 15)))*8 + j] = f2bs(vv[t]);
        }
    }

    float bkc[8];
    #pragma unroll
    for (int n0i = 0; n0i < 8; n0i++) bkc[n0i] = bk[n0i*16 + m16];
    __syncthreads();

    float colsum[8] = {0.f,0.f,0.f,0.f,0.f,0.f,0.f,0.f};

    int tile = blockIdx.x;
    frag_ab a0 = {}, a1 = {}, a2 = {}, a3 = {};
    frag_ab p0 = {}, p1 = {}, p2 = {}, p3 = {};
    if (tile < nt) SEMW_LOADA(a, tile)
    while (tile < nt){
        const int tnext = tile + gridDim.x;
        if (tnext < nt) SEMW_LOADA(p, tnext)

        frag_cd acc[8];
        #pragma unroll
        for (int n0i = 0; n0i < 8; n0i++) acc[n0i] = (frag_cd){0.f,0.f,0.f,0.f};
        #pragma unroll
        for (int n0i = 0; n0i < 8; n0i++){
            acc[n0i] = __builtin_amdgcn_mfma_f32_16x16x32_bf16(a0,
                *(const frag_ab*)&Bs[((0*8 + n0i)*64 + lane)*8], acc[n0i], 0, 0, 0);
            acc[n0i] = __builtin_amdgcn_mfma_f32_16x16x32_bf16(a1,
                *(const frag_ab*)&Bs[((1*8 + n0i)*64 + lane)*8], acc[n0i], 0, 0, 0);
            acc[n0i] = __builtin_amdgcn_mfma_f32_16x16x32_bf16(a2,
                *(const frag_ab*)&Bs[((2*8 + n0i)*64 + lane)*8], acc[n0i], 0, 0, 0);
            acc[n0i] = __builtin_amdgcn_mfma_f32_16x16x32_bf16(a3,
                *(const frag_ab*)&Bs[((3*8 + n0i)*64 + lane)*8], acc[n0i], 0, 0, 0);
        }

        // D: row = tile*64 + w*16 + quad*4 + r, col = n0i*16 + m16
        const int row0 = tile*64 + w*16 + quad*4;
        #pragma unroll
        for (int n0i = 0; n0i < 8; n0i++){
            float part = 0.f;
            #pragma unroll
            for (int r = 0; r < 4; r++)
                if (row0 + r < Na) part += fast_tanh(acc[n0i][r] + bkc[n0i]);
            part += __shfl_down(part, 32);
            part += __shfl_down(part, 16);
            if (lane < 16) colsum[n0i] += part;
        }

        if (tnext < nt){ a0 = p0; a1 = p1; a2 = p2; a3 = p3; }
        tile = tnext;
    }

    // cross-wave reduce, then 128 atomics per block
    if (lane < 16){
        #pragma unroll
        for (int n0i = 0; n0i < 8; n0i++) csum[w][n0i][lane] = colsum[n0i];
    }
    __syncthreads();
    if (tid < 128){
        const int n0i = tid >> 4, l16 = tid & 15;
        const float v = csum[0][n0i][l16] + csum[1][n0i][l16]
                      + csum[2][n0i][l16] + csum[3][n0i][l16];
        unsafeAtomicAdd(&wsum[blockIdx.y*128 + n0i*16 + l16], v);
    }
}

// beta = softmax over 2 of ((wsum/Na) . q)
__global__ void beta_kernel(const float* __restrict__ wsum, const float* __restrict__ q,
                            float* __restrict__ beta, float invN)
{
    __shared__ float r0s[128], r1s[128];
    const int tid = threadIdx.x;
    const float qv = q[tid];
    r0s[tid] = wsum[tid]     * invN * qv;
    r1s[tid] = wsum[128+tid] * invN * qv;
    __syncthreads();
    for (int st = 64; st > 0; st >>= 1){
        if (tid < st){ r0s[tid] += r0s[tid+st]; r1s[tid] += r1s[tid+st]; }
        __syncthreads();
    }
    if (tid == 0){
        const float w0 = r0s[0], w1 = r1s[0];
        const float m = fmaxf(w0, w1);
        const float e0 = __expf(w0-m), e1 = __expf(w1-m);
        const float inv = 1.f/(e0+e1);
        beta[0] = e0*inv; beta[1] = e1*inv;
    }
}

// sem = b0*n_pa + b1*n_da (bf16, already relu'd+normalized); logits=sem@Wl+bl; softmax
__global__ __launch_bounds__(256) void final_kernel(
    const unsigned* __restrict__ n_pa, const unsigned* __restrict__ n_da,
    const float* __restrict__ beta,
    const float* __restrict__ Wl, const float* __restrict__ bl,
    float* __restrict__ out, int Na)
{
    const int gtid = blockIdx.x*256 + threadIdx.x;
    const int node = gtid >> 6;
    const int lane = threadIdx.x & 63;
    if (node >= Na) return;
    const float b0 = beta[0], b1 = beta[1];
    const unsigned up = n_pa[(size_t)node*64 + lane];
    const unsigned ud = n_da[(size_t)node*64 + lane];
    const float sm0 = b0*blo(up) + b1*blo(ud);   // col 2*lane
    const float sm1 = b0*bhi(up) + b1*bhi(ud);   // col 2*lane+1
    const float4 wv = *(const float4*)&Wl[lane*4];  // rows 2l,2l+1 of Wl[128][2]
    float l0 = sm0*wv.x + sm1*wv.z;
    float l1 = sm0*wv.y + sm1*wv.w;
    #pragma unroll
    for (int off = 32; off > 0; off >>= 1){
        l0 += __shfl_down(l0, off);
        l1 += __shfl_down(l1, off);
    }
    if (lane == 0){
        l0 += bl[0]; l1 += bl[1];
        const float m = fmaxf(l0, l1);
        const float e0 = __expf(l0-m), e1 = __expf(l1-m);
        const float inv = 1.f/(e0+e1);
        out[(size_t)node*2+0] = e0*inv;
        out[(size_t)node*2+1] = e1*inv;
    }
}

// ---------------------------------------------------------------------------
extern "C" void kernel_launch(void* const* d_in, const int* in_sizes, int n_in,
                              void* d_out, int out_size, void* d_ws, size_t ws_size,
                              hipStream_t stream)
{
    const float* x_adm    = (const float*)d_in[0];
    const float* x_pat    = (const float*)d_in[1];
    const float* x_diag   = (const float*)d_in[2];
    const int*   e_pa_src = (const int*)d_in[3];
    const int*   e_pa_dst = (const int*)d_in[4];
    const int*   e_da_src = (const int*)d_in[5];
    const int*   e_da_dst = (const int*)d_in[6];
    const float* Wa = (const float*)d_in[7];
    const float* ba = (const float*)d_in[8];
    const float* Wp = (const float*)d_in[9];
    const float* bp = (const float*)d_in[10];
    const float* Wd = (const float*)d_in[11];
    const float* bd = (const float*)d_in[12];
    const float* ats_pa = (const float*)d_in[13];
    const float* atd_pa = (const float*)d_in[14];
    const float* ats_da = (const float*)d_in[15];
    const float* atd_da = (const float*)d_in[16];
    const float* Wk = (const float*)d_in[17];
    const float* bk = (const float*)d_in[18];
    const float* q  = (const float*)d_in[19];
    const float* Wl = (const float*)d_in[20];
    const float* bl = (const float*)d_in[21];

    const int Na  = in_sizes[0] / 128;
    const int Np  = in_sizes[1] / 64;
    const int Nd  = in_sizes[2] / 64;
    const int Epa = in_sizes[3];
    const int Eda = in_sizes[5];

    float* ws = (float*)d_ws;
    size_t off = 0;
    // --- zero-initialized region (contiguous, one small memset) ---
    int*   cnt_pa = (int*)(ws + off); off += Na;   // histogram counts -> cursor
    int*   cnt_da = (int*)(ws + off); off += Na;
    float* wsum   = ws + off; off += 256;
    float* beta   = ws + off; off += 8;
    const size_t zero_len = off;
    // --- fully-overwritten region ---
    off = (off + 3) & ~(size_t)3;                  // 16B align
    unsigned* n_pa = (unsigned*)(ws + off); off += (size_t)Na*64;  // [Na,64] dwords
    unsigned* n_da = (unsigned*)(ws + off); off += (size_t)Na*64;
    float* a_s_pa = ws + off; off += (size_t)Np*8;
    float* a_s_da = ws + off; off += (size_t)Nd*8;
    float* a_d_pa = ws + off; off += (size_t)Na*8;
    float* a_d_da = ws + off; off += (size_t)Na*8;
    float* Wf     = ws + off; off += 2048;
    float* bdot   = ws + off; off += 16;
    bf16*  h_p    = (bf16*)(ws + off); off += (size_t)Np*64;
    bf16*  h_d    = (bf16*)(ws + off); off += (size_t)Nd*64;
    int*   rowptr_pa = (int*)(ws + off); off += (size_t)Na + 1;
    int*   rowptr_da = (int*)(ws + off); off += (size_t)Na + 1;
    int*   sorted_pa = (int*)(ws + off); off += (size_t)Epa;
    int*   sorted_da = (int*)(ws + off); off += (size_t)Eda;
    int*   bsum_pa   = (int*)(ws + off); off += 256;
    int*   bsum_da   = (int*)(ws + off); off += 256;
    (void)n_in; (void)out_size; (void)ws_size; (void)off;

    hipMemsetAsync(d_ws, 0, zero_len*sizeof(float), stream);

    // fold attention into adm projection; thin GEMM for a_d (h_adm never built)
    prep_fold<<<1,128,0,stream>>>(Wa, ba, atd_pa, atd_da, Wf, bdot);
    {
        const int nt = (Na + 15)/16;
        afold_kernel<<<imin(nt,4096),256,0,stream>>>(x_adm, Wf, bdot,
                                                     a_d_pa, a_d_da, Na, nt);
    }
    // pat/diag projections (h stored bf16 + a_s dots)
    {
        const int nt = (Np + 31)/32;
        proj64<<<imin(nt,1024),256,0,stream>>>(x_pat, Wp, bp, ats_pa, h_p, a_s_pa, Np, nt);
    }
    {
        const int nt = (Nd + 31)/32;
        proj64<<<imin(nt,1024),256,0,stream>>>(x_diag, Wd, bd, ats_da, h_d, a_s_da, Nd, nt);
    }

    // --- counting sort of edges by dst (CSR) ---
    const int nbkt = (Na + 4095)/4096;
    hist_kernel<<<(Epa+255)/256, 256, 0, stream>>>(e_pa_dst, cnt_pa, Epa);
    hist_kernel<<<(Eda+255)/256, 256, 0, stream>>>(e_da_dst, cnt_da, Eda);
    scan_bsum<<<nbkt, 256, 0, stream>>>(cnt_pa, bsum_pa, Na);
    scan_bsum<<<nbkt, 256, 0, stream>>>(cnt_da, bsum_da, Na);
    scan_excl<<<1, 256, 0, stream>>>(bsum_pa, nbkt);
    scan_excl<<<1, 256, 0, stream>>>(bsum_da, nbkt);
    scan_write<<<nbkt, 256, 0, stream>>>(cnt_pa, bsum_pa, rowptr_pa, Na);
    scan_write<<<nbkt, 256, 0, stream>>>(cnt_da, bsum_da, rowptr_da, Na);
    scatter_kernel<<<(Epa+255)/256, 256, 0, stream>>>(e_pa_src, e_pa_dst, cnt_pa, sorted_pa, Epa);
    scatter_kernel<<<(Eda+255)/256, 256, 0, stream>>>(e_da_src, e_da_dst, cnt_da, sorted_da, Eda);

    // --- gather-aggregate (both edge types, 16 lanes/node) -> bf16 n arrays ---
    gather_kernel<<<(2*Na+15)/16, 256, 0, stream>>>(
        rowptr_pa, sorted_pa, a_s_pa, a_d_pa, h_p, n_pa,
        rowptr_da, sorted_da, a_s_da, a_d_da, h_d, n_da, Na);

    // semantic attention (MFMA on bf16 n; barrier-free main loop, A from global)
    {
        const int nt = (Na + 63)/64;
        dim3 grid(imin(nt, 512), 2);
        semw_mfma<<<grid, 256, 0, stream>>>(n_pa, n_da, Wk, bk, wsum, Na, nt);
    }
    beta_kernel<<<1,128,0,stream>>>(wsum, q, beta, 1.f/(float)Na);

    // combine + classifier + softmax (reads bf16 n arrays)
    final_kernel<<<(Na+3)/4, 256, 0, stream>>>(n_pa, n_da, beta,
                                               Wl, bl, (float*)d_out, Na);
}